// Round 5
// baseline (273.218 us; speedup 1.0000x reference)
//
#include <hip/hip_runtime.h>
#include <math.h>

#define N_TOK 4096
#define CIN 256
#define CBN 64
#define LOG2E 1.44269504f

typedef __attribute__((ext_vector_type(8))) short bf16x8;
typedef __attribute__((ext_vector_type(4))) float f32x4;

static __device__ __forceinline__ unsigned short f2bf(float f) {
    union { float f; unsigned u; } v; v.f = f;
    unsigned r = v.u + 0x7fffu + ((v.u >> 16) & 1u);
    return (unsigned short)(r >> 16);
}
static __device__ __forceinline__ unsigned pack2(float a, float b) {
    return (unsigned)f2bf(a) | ((unsigned)f2bf(b) << 16);
}

// ---------------- kernel 1: transpose weights (fp32) ----------------
// w_q (and b_q) pre-scaled by log2(e) so attention uses exp2 directly.
__global__ __launch_bounds__(256) void prep_w(
        const float* __restrict__ wq, const float* __restrict__ wk,
        const float* __restrict__ wv, const float* __restrict__ wu,
        const float* __restrict__ bq,
        float* __restrict__ wTq, float* __restrict__ wTk,
        float* __restrict__ wTv, float* __restrict__ wuT,
        float* __restrict__ bqs) {
    int idx = blockIdx.x * 256 + threadIdx.x;   // 0..16383
    int d = idx >> 8, c = idx & 255;            // w*[d][c] -> wT[c][d]
    wTq[c * 64 + d] = wq[idx] * LOG2E;
    wTk[c * 64 + d] = wk[idx];
    wTv[c * 64 + d] = wv[idx];
    int c2 = idx >> 6, d2 = idx & 63;           // wu[c2][d2] -> wuT[d2][c2]
    wuT[d2 * 256 + c2] = wu[idx];
    if (idx < 64) bqs[idx] = bq[idx] * LOG2E;
}

// ---------------- kernel 2: QKV projection ----------------
// Q,K token-major [B][N][64] bf16; V d-major [B][64][N] bf16 with columns
// PERMUTED inside each 32-token block: col' = 8*((u>>2)&3) + 4*(u>>4) + (u&3)
// (u = token & 31) so attn's PV A-fragment matches the in-register P slots.
// 1024 blocks x 256 thr; 2 d x 2 tokens per thread -> 4 waves/SIMD.
__global__ __launch_bounds__(256) void qkv_kernel(
        const float* __restrict__ x,
        const float* __restrict__ wTq, const float* __restrict__ wTk, const float* __restrict__ wTv,
        const float* __restrict__ bq, const float* __restrict__ bk, const float* __restrict__ bv,
        short* __restrict__ Qt, short* __restrict__ Kt, short* __restrict__ Vd) {
    int t = threadIdx.x;
    int tg = t & 31;       // token pair: tokens tg*2, tg*2+1
    int dg = t >> 5;       // 0..7
    int blk = blockIdx.x;  // B * 64 * 4 = 1024
    int b = blk >> 8;
    int rem = blk & 255;
    int n0 = (rem >> 2) * 64;
    int d0 = (rem & 3) * 16 + dg * 2;    // 2 d per thread
    const float* xb = x + (size_t)b * CIN * N_TOK + n0 + tg * 2;

    float aq[2][2] = {}, ak[2][2] = {}, av[2][2] = {};
    #pragma unroll 8
    for (int c = 0; c < CIN; ++c) {
        float2 xv = *(const float2*)(xb + (size_t)c * N_TOK);
        float2 q2 = *(const float2*)(wTq + c * 64 + d0);
        float2 k2 = *(const float2*)(wTk + c * 64 + d0);
        float2 v2 = *(const float2*)(wTv + c * 64 + d0);
        float xs[2] = {xv.x, xv.y};
        float qs[2] = {q2.x, q2.y};
        float ks[2] = {k2.x, k2.y};
        float vs[2] = {v2.x, v2.y};
        #pragma unroll
        for (int i = 0; i < 2; ++i)
            #pragma unroll
            for (int j = 0; j < 2; ++j) {
                aq[i][j] = fmaf(qs[i], xs[j], aq[i][j]);
                ak[i][j] = fmaf(ks[i], xs[j], ak[i][j]);
                av[i][j] = fmaf(vs[i], xs[j], av[i][j]);
            }
    }
    float bqr[2] = {bq[d0], bq[d0 + 1]};
    float bkr[2] = {bk[d0], bk[d0 + 1]};
    float bvr[2] = {bv[d0], bv[d0 + 1]};
    // Q,K: token-major stores (2 consecutive d per token -> one u32)
    #pragma unroll
    for (int j = 0; j < 2; ++j) {
        int n = n0 + tg * 2 + j;
        size_t qo = ((size_t)b * N_TOK + n) * 64 + d0;
        *(unsigned*)(Qt + qo) = pack2(aq[0][j] + bqr[0], aq[1][j] + bqr[1]);
        *(unsigned*)(Kt + qo) = pack2(ak[0][j] + bkr[0], ak[1][j] + bkr[1]);
    }
    // V: d-major, swizzled column (2 tokens stay adjacent -> one u32)
    {
        int tt = tg * 2;
        int u = tt & 31;
        int vcol = n0 + (tt & 32) + 8 * ((u >> 2) & 3) + 4 * (u >> 4) + (u & 3);
        #pragma unroll
        for (int i = 0; i < 2; ++i) {
            size_t vo = ((size_t)b * 64 + d0 + i) * N_TOK + vcol;
            *(unsigned*)(Vd + vo) = pack2(av[i][0] + bvr[i], av[i][1] + bvr[i]);
        }
    }
}

// ---------------- kernel 3: flash attention, zero-LDS inner loop ----------
// 4 waves/block; each wave = same 16 queries, disjoint 1024-key range.
// S^T = mfma(K,Q): lane (g,lr) gets s[nt][r] = P[16nt+4g+r][query=lr].
// PV B-fragment slot (g,e) = key 32ks+16(e>>2)+4g+(e&3) -> the lane's OWN
// s registers (no exchange); V stored with matching column permutation.
// No LDS / barriers / waitcnt inside the loop -> compiler pipelines freely.
__global__ __launch_bounds__(256, 4) void attn_kernel(
        const short* __restrict__ Qt, const short* __restrict__ Kt,
        const short* __restrict__ Vsw, float* __restrict__ O) {
    int t = threadIdx.x;
    int w = t >> 6;        // wave 0..3 -> key range
    int g = (t >> 4) & 3;  // lane group 0..3
    int lr = t & 15;
    int bid = blockIdx.x;
    int blk = ((bid & 7) << 7) | (bid >> 3);   // XCD swizzle, bijective
    int b = blk >> 8;
    int q0 = (blk & 255) * 16;

    const short* Qb = Qt + (size_t)b * N_TOK * 64;
    const short* Kb = Kt + (size_t)b * N_TOK * 64;
    const short* Vb = Vsw + (size_t)b * 64 * N_TOK;

    bf16x8 qf0 = *(const bf16x8*)(Qb + (q0 + lr) * 64 + 8 * g);
    bf16x8 qf1 = *(const bf16x8*)(Qb + (q0 + lr) * 64 + 32 + 8 * g);

    f32x4 o[4];
    #pragma unroll
    for (int mt = 0; mt < 4; ++mt) o[mt] = (f32x4){0.f, 0.f, 0.f, 0.f};
    float lacc = 0.f;

    __shared__ float Om[4][64][17];    // per-wave unnormalized O partial
    __shared__ float Ml[4][16];        // per-wave l per query

    for (int kt = 0; kt < 16; ++kt) {
        int k0 = (w * 16 + kt) * 64;
        // ---- S^T = K·Q^T : row = key (4g+r), col = query (lr) ----
        f32x4 s[4];
        #pragma unroll
        for (int nt = 0; nt < 4; ++nt) {
            const short* kp = Kb + (k0 + nt * 16 + lr) * 64 + 8 * g;
            bf16x8 kf0 = *(const bf16x8*)kp;
            bf16x8 kf1 = *(const bf16x8*)(kp + 32);
            f32x4 z = (f32x4){0.f, 0.f, 0.f, 0.f};
            z = __builtin_amdgcn_mfma_f32_16x16x32_bf16(kf0, qf0, z, 0, 0, 0);
            s[nt] = __builtin_amdgcn_mfma_f32_16x16x32_bf16(kf1, qf1, z, 0, 0, 0);
        }
        // ---- p = 2^s ; in-lane l accumulation ----
        #pragma unroll
        for (int nt = 0; nt < 4; ++nt)
            #pragma unroll
            for (int r = 0; r < 4; ++r) {
                float p = exp2f(s[nt][r]);
                s[nt][r] = p;
                lacc += p;
            }
        // ---- pack P to bf16 B-fragments in-register (slot-consistent) ----
        bf16x8 bp0, bp1;
        #pragma unroll
        for (int e = 0; e < 8; ++e) {
            bp0[e] = (short)f2bf(s[e >> 2][e & 3]);
            bp1[e] = (short)f2bf(s[2 + (e >> 2)][e & 3]);
        }
        // ---- O^T[d][q] += V·P (V pre-swizzled to the same slot order) ----
        #pragma unroll
        for (int mt = 0; mt < 4; ++mt) {
            const short* vp = Vb + (mt * 16 + lr) * N_TOK + k0 + 8 * g;
            bf16x8 av0 = *(const bf16x8*)vp;         // keys [k0, k0+32)
            bf16x8 av1 = *(const bf16x8*)(vp + 32);  // keys [k0+32, k0+64)
            o[mt] = __builtin_amdgcn_mfma_f32_16x16x32_bf16(av0, bp0, o[mt], 0, 0, 0);
            o[mt] = __builtin_amdgcn_mfma_f32_16x16x32_bf16(av1, bp1, o[mt], 0, 0, 0);
        }
    }
    // ---- l: reduce across the 4 lane-groups (all keys of this wave) ----
    lacc += __shfl_xor(lacc, 16);
    lacc += __shfl_xor(lacc, 32);
    // ---- per-wave partials to LDS ----
    #pragma unroll
    for (int mt = 0; mt < 4; ++mt)
        #pragma unroll
        for (int r = 0; r < 4; ++r)
            Om[w][mt * 16 + 4 * g + r][lr] = o[mt][r];
    Ml[w][lr] = lacc;
    __syncthreads();
    // ---- merge 4 wave-partials (plain sums), normalize, store ----
    {
        int q = t & 15, dq = t >> 4;   // 16 d-groups x 4 d
        float lsum = Ml[0][q] + Ml[1][q] + Ml[2][q] + Ml[3][q];
        float inv = 1.f / lsum;
        #pragma unroll
        for (int i = 0; i < 4; ++i) {
            int d = dq * 4 + i;
            float v = Om[0][d][q] + Om[1][d][q] + Om[2][d][q] + Om[3][d][q];
            O[((size_t)b * 64 + d) * N_TOK + q0 + q] = v * inv;
        }
    }
}

// ---------------- kernel 4: up-projection + bias + residual ----------------
// 2048 blocks; 2 c x 4 tokens per thread -> 8 waves/SIMD.
__global__ __launch_bounds__(256) void out_kernel(
        const float* __restrict__ O, const float* __restrict__ wuT,
        const float* __restrict__ bu, const float* __restrict__ x,
        float* __restrict__ y) {
    int t = threadIdx.x;
    int tg = t & 15, cg = t >> 4;
    int blk = blockIdx.x;          // B * 64 tok-tiles * 8 c-octants
    int b = blk >> 9;
    int rem = blk & 511;
    int ntile = rem >> 3, cq = rem & 7;
    int n0 = ntile * 64;
    int c0 = cq * 32 + cg * 2;
    const float* Ob = O + (size_t)b * 64 * N_TOK + n0 + tg * 4;
    const float* wb = wuT + c0;

    float acc[2][4] = {};
    #pragma unroll 4
    for (int d = 0; d < 64; ++d) {
        float4 ov = *(const float4*)(Ob + (size_t)d * N_TOK);
        float2 wv = *(const float2*)(wb + d * 256);
        float os[4] = {ov.x, ov.y, ov.z, ov.w};
        float wsr[2] = {wv.x, wv.y};
        #pragma unroll
        for (int i = 0; i < 2; ++i)
            #pragma unroll
            for (int j = 0; j < 4; ++j)
                acc[i][j] = fmaf(wsr[i], os[j], acc[i][j]);
    }
    #pragma unroll
    for (int i = 0; i < 2; ++i) {
        int c = c0 + i;
        float bc = bu[c];
        size_t xo = ((size_t)b * CIN + c) * N_TOK + n0 + tg * 4;
        float4 xr = *(const float4*)(x + xo);
        float4 yo;
        yo.x = acc[i][0] + bc + xr.x;
        yo.y = acc[i][1] + bc + xr.y;
        yo.z = acc[i][2] + bc + xr.z;
        yo.w = acc[i][3] + bc + xr.w;
        *(float4*)(y + xo) = yo;
    }
}

extern "C" void kernel_launch(void* const* d_in, const int* in_sizes, int n_in,
                              void* d_out, int out_size, void* d_ws, size_t ws_size,
                              hipStream_t stream) {
    const float* x  = (const float*)d_in[0];
    const float* wk = (const float*)d_in[1];
    const float* bk = (const float*)d_in[2];
    const float* wq = (const float*)d_in[3];
    const float* bq = (const float*)d_in[4];
    const float* wv = (const float*)d_in[5];
    const float* bv = (const float*)d_in[6];
    const float* wu = (const float*)d_in[7];
    const float* bu = (const float*)d_in[8];
    float* out = (float*)d_out;

    char* ws = (char*)d_ws;
    if (ws_size < (size_t)(10u << 20) + 263168u) return;  // ~10.25 MB
    short* Qt  = (short*)(ws);                       // 2 MB  [B][N][64] bf16
    short* Kt  = (short*)(ws + (2u << 20));          // 2 MB
    short* Vd  = (short*)(ws + (4u << 20));          // 2 MB  [B][64][N] bf16 (swizzled cols)
    float* O   = (float*)(ws + (6u << 20));          // 4 MB  [B][64][N] f32
    float* wTq = (float*)(ws + (10u << 20));         // 64 KB each
    float* wTk = wTq + 16384;
    float* wTv = wTk + 16384;
    float* wuT = wTv + 16384;
    float* bqs = wuT + 16384;                        // 64 floats (scaled b_q)

    prep_w<<<dim3(64), dim3(256), 0, stream>>>(wq, wk, wv, wu, bq, wTq, wTk, wTv, wuT, bqs);
    qkv_kernel<<<dim3(1024), dim3(256), 0, stream>>>(x, wTq, wTk, wTv, bqs, bk, bv, Qt, Kt, Vd);
    attn_kernel<<<dim3(1024), dim3(256), 0, stream>>>(Qt, Kt, Vd, O);
    out_kernel<<<dim3(2048), dim3(256), 0, stream>>>(O, wuT, bu, x, out);
}

// Round 6
// 151.502 us; speedup vs baseline: 1.8034x; 1.8034x over previous
//
#include <hip/hip_runtime.h>
#include <math.h>

#define N_TOK 4096
#define CIN 256
#define CBN 64
#define LOG2E 1.44269504f

typedef __attribute__((ext_vector_type(8))) short bf16x8;
typedef __attribute__((ext_vector_type(4))) float f32x4;

static __device__ __forceinline__ unsigned short f2bf(float f) {
    union { float f; unsigned u; } v; v.f = f;
    unsigned r = v.u + 0x7fffu + ((v.u >> 16) & 1u);
    return (unsigned short)(r >> 16);
}
static __device__ __forceinline__ unsigned pack2(float a, float b) {
    return (unsigned)f2bf(a) | ((unsigned)f2bf(b) << 16);
}

// ---------------- kernel 1: weight prep ----------------
// Wb bf16 [192][256]: rows 0-63 = wq*log2e, 64-127 = wk, 128-191 = wv.
// Wu bf16 [256][64] = wu converted in place-layout. bqs = bq*log2e (fp32).
__global__ __launch_bounds__(256) void prep_w(
        const float* __restrict__ wq, const float* __restrict__ wk,
        const float* __restrict__ wv, const float* __restrict__ wu,
        const float* __restrict__ bq,
        short* __restrict__ Wb, short* __restrict__ Wu, float* __restrict__ bqs) {
    int idx = blockIdx.x * 256 + threadIdx.x;   // 0..16383
    int d = idx >> 8, c = idx & 255;            // w*[d][c]
    Wb[d * 256 + c]         = (short)f2bf(wq[idx] * LOG2E);
    Wb[(64 + d) * 256 + c]  = (short)f2bf(wk[idx]);
    Wb[(128 + d) * 256 + c] = (short)f2bf(wv[idx]);
    Wu[idx] = (short)f2bf(wu[idx]);             // wu already [256][64]
    if (idx < 64) bqs[idx] = bq[idx] * LOG2E;
}

// ---------------- kernel 2: QKV projection (MFMA) ----------------
// Block = 16 tokens. Stage x-tile [16 tok][256 c] -> LDS bf16 (transposed),
// one barrier, then pure MFMA: wave w computes 16-d tile of Q, K and V.
// Q,K token-major [B][N][64]; V d-major [B][64][N] with the verified
// in-32 column permutation col' = 8*((u>>2)&3) + 4*(u>>4) + (u&3).
__global__ __launch_bounds__(256) void qkv_kernel(
        const float* __restrict__ x, const short* __restrict__ Wb,
        const float* __restrict__ bqs, const float* __restrict__ bk, const float* __restrict__ bv,
        short* __restrict__ Qt, short* __restrict__ Kt, short* __restrict__ Vd) {
    int t = threadIdx.x;
    int blk = blockIdx.x;           // 1024 = B(4) * 256 token-tiles
    int b = blk >> 8;
    int n0 = (blk & 255) * 16;

    __shared__ short Xs[16][264];   // [tok][c], 528B rows (16B-aligned)

    // ---- stage: coalesced float4 along tokens, transpose into LDS ----
    {
        int tok4 = t & 3;           // token quad 0..3 -> tokens 4*tok4..+3
        int cb = t >> 2;            // 64 c per pass
        const float* xb = x + (size_t)b * CIN * N_TOK + n0 + tok4 * 4;
        #pragma unroll
        for (int p = 0; p < 4; ++p) {
            int c = p * 64 + cb;
            float4 xv = *(const float4*)(xb + (size_t)c * N_TOK);
            float xs[4] = {xv.x, xv.y, xv.z, xv.w};
            #pragma unroll
            for (int i = 0; i < 4; ++i)
                Xs[tok4 * 4 + i][c] = (short)f2bf(xs[i]);
        }
    }
    __syncthreads();

    int w = t >> 6;         // wave -> d-tile index (0..3)
    int g = (t >> 4) & 3;
    int lr = t & 15;

    // A[row=lr][k=8g+j] = Wb[mat*64 + w*16 + lr][32ks + 8g + j]
    // B[k=8g+j][n=lr]  = Xs[lr][32ks + 8g + j]
    f32x4 acc[3];
    #pragma unroll
    for (int m = 0; m < 3; ++m) acc[m] = (f32x4){0.f, 0.f, 0.f, 0.f};
    const short* wbase = Wb + (size_t)(w * 16 + lr) * 256 + 8 * g;
    #pragma unroll
    for (int ks = 0; ks < 8; ++ks) {
        bf16x8 xf = *(const bf16x8*)&Xs[lr][ks * 32 + 8 * g];
        #pragma unroll
        for (int m = 0; m < 3; ++m) {
            bf16x8 wf = *(const bf16x8*)(wbase + (size_t)m * 64 * 256 + ks * 32);
            acc[m] = __builtin_amdgcn_mfma_f32_16x16x32_bf16(wf, xf, acc[m], 0, 0, 0);
        }
    }
    // D: row = 4g+r -> d = w*16 + 4g + r ; col = lr -> tok = n0 + lr
    int d0 = w * 16 + 4 * g;
    int tok = n0 + lr;
    float4 bq4 = *(const float4*)(bqs + d0);
    float4 bk4 = *(const float4*)(bk + d0);
    float4 bv4 = *(const float4*)(bv + d0);
    size_t qo = ((size_t)b * N_TOK + tok) * 64 + d0;
    uint2 qp, kp;
    qp.x = pack2(acc[0][0] + bq4.x, acc[0][1] + bq4.y);
    qp.y = pack2(acc[0][2] + bq4.z, acc[0][3] + bq4.w);
    kp.x = pack2(acc[1][0] + bk4.x, acc[1][1] + bk4.y);
    kp.y = pack2(acc[1][2] + bk4.z, acc[1][3] + bk4.w);
    *(uint2*)(Qt + qo) = qp;
    *(uint2*)(Kt + qo) = kp;
    // V: d-major with permuted column
    int u = tok & 31;
    int vcol = (tok & ~31) + 8 * ((u >> 2) & 3) + 4 * (u >> 4) + (u & 3);
    float bvr[4] = {bv4.x, bv4.y, bv4.z, bv4.w};
    #pragma unroll
    for (int r = 0; r < 4; ++r)
        Vd[((size_t)b * 64 + d0 + r) * N_TOK + vcol] = (short)f2bf(acc[2][r] + bvr[r]);
}

// ---------------- kernel 3: flash attention, zero-LDS inner loop ----------
// 4 waves/block; each wave = same 16 queries, disjoint 1024-key range.
// Static softmax (scores bounded ~15): S^T = mfma(K,Q) -> l-sum in-lane,
// P packed to B-fragments in-register, V pre-permuted to match slots.
__global__ __launch_bounds__(256) void attn_kernel(
        const short* __restrict__ Qt, const short* __restrict__ Kt,
        const short* __restrict__ Vsw, short* __restrict__ Otm) {
    int t = threadIdx.x;
    int w = t >> 6;        // wave 0..3 -> key range
    int g = (t >> 4) & 3;  // lane group 0..3
    int lr = t & 15;
    int bid = blockIdx.x;
    int blk = ((bid & 7) << 7) | (bid >> 3);   // XCD swizzle, bijective
    int b = blk >> 8;
    int q0 = (blk & 255) * 16;

    const short* Qb = Qt + (size_t)b * N_TOK * 64;
    const short* Kb = Kt + (size_t)b * N_TOK * 64;
    const short* Vb = Vsw + (size_t)b * 64 * N_TOK;

    bf16x8 qf0 = *(const bf16x8*)(Qb + (q0 + lr) * 64 + 8 * g);
    bf16x8 qf1 = *(const bf16x8*)(Qb + (q0 + lr) * 64 + 32 + 8 * g);

    f32x4 o[4];
    #pragma unroll
    for (int mt = 0; mt < 4; ++mt) o[mt] = (f32x4){0.f, 0.f, 0.f, 0.f};
    float lacc = 0.f;

    __shared__ float Om[4][64][17];    // per-wave unnormalized O partial
    __shared__ float Ml[4][16];        // per-wave l per query

    for (int kt = 0; kt < 16; ++kt) {
        int k0 = (w * 16 + kt) * 64;
        // ---- S^T = K·Q^T : row = key (4g+r), col = query (lr) ----
        f32x4 s[4];
        #pragma unroll
        for (int nt = 0; nt < 4; ++nt) {
            const short* kp = Kb + (k0 + nt * 16 + lr) * 64 + 8 * g;
            bf16x8 kf0 = *(const bf16x8*)kp;
            bf16x8 kf1 = *(const bf16x8*)(kp + 32);
            f32x4 z = (f32x4){0.f, 0.f, 0.f, 0.f};
            z = __builtin_amdgcn_mfma_f32_16x16x32_bf16(kf0, qf0, z, 0, 0, 0);
            s[nt] = __builtin_amdgcn_mfma_f32_16x16x32_bf16(kf1, qf1, z, 0, 0, 0);
        }
        // ---- p = 2^s ; in-lane l accumulation ----
        #pragma unroll
        for (int nt = 0; nt < 4; ++nt)
            #pragma unroll
            for (int r = 0; r < 4; ++r) {
                float p = exp2f(s[nt][r]);
                s[nt][r] = p;
                lacc += p;
            }
        // ---- pack P to bf16 B-fragments in-register (slot-consistent) ----
        bf16x8 bp0, bp1;
        #pragma unroll
        for (int e = 0; e < 8; ++e) {
            bp0[e] = (short)f2bf(s[e >> 2][e & 3]);
            bp1[e] = (short)f2bf(s[2 + (e >> 2)][e & 3]);
        }
        // ---- O^T[d][q] += V·P (V pre-swizzled to the same slot order) ----
        #pragma unroll
        for (int mt = 0; mt < 4; ++mt) {
            const short* vp = Vb + (mt * 16 + lr) * N_TOK + k0 + 8 * g;
            bf16x8 av0 = *(const bf16x8*)vp;         // keys [k0, k0+32)
            bf16x8 av1 = *(const bf16x8*)(vp + 32);  // keys [k0+32, k0+64)
            o[mt] = __builtin_amdgcn_mfma_f32_16x16x32_bf16(av0, bp0, o[mt], 0, 0, 0);
            o[mt] = __builtin_amdgcn_mfma_f32_16x16x32_bf16(av1, bp1, o[mt], 0, 0, 0);
        }
    }
    // ---- l: reduce across the 4 lane-groups (all keys of this wave) ----
    lacc += __shfl_xor(lacc, 16);
    lacc += __shfl_xor(lacc, 32);
    // ---- per-wave partials to LDS ----
    #pragma unroll
    for (int mt = 0; mt < 4; ++mt)
        #pragma unroll
        for (int r = 0; r < 4; ++r)
            Om[w][mt * 16 + 4 * g + r][lr] = o[mt][r];
    Ml[w][lr] = lacc;
    __syncthreads();
    // ---- merge 4 wave-partials, normalize, store O token-major bf16 ----
    {
        int q = t & 15, dq = t >> 4;   // 16 d-groups x 4 d
        float lsum = Ml[0][q] + Ml[1][q] + Ml[2][q] + Ml[3][q];
        float inv = 1.f / lsum;
        float v[4];
        #pragma unroll
        for (int i = 0; i < 4; ++i) {
            int d = dq * 4 + i;
            v[i] = (Om[0][d][q] + Om[1][d][q] + Om[2][d][q] + Om[3][d][q]) * inv;
        }
        uint2 ow;
        ow.x = pack2(v[0], v[1]);
        ow.y = pack2(v[2], v[3]);
        *(uint2*)(Otm + ((size_t)b * N_TOK + q0 + q) * 64 + dq * 4) = ow;
    }
}

// ---------------- kernel 4: up-projection + bias + residual (MFMA) --------
// A = Otm[tok][d] (16B contiguous), B = Wu[c][d] (16B contiguous).
// D: row=4g+r -> token, col=lr -> c  => float4 y stores + float4 x residual.
__global__ __launch_bounds__(256) void out_kernel(
        const short* __restrict__ Otm, const short* __restrict__ Wu,
        const float* __restrict__ bu, const float* __restrict__ x,
        float* __restrict__ y) {
    int t = threadIdx.x;
    int w = t >> 6, g = (t >> 4) & 3, lr = t & 15;
    int blk = blockIdx.x;          // 1024 = B(4) * 64 tok-tiles * 4 c-blocks
    int b = blk >> 8;
    int rem = blk & 255;
    int nblk = rem >> 2, cblk = rem & 3;
    int n0 = nblk * 64 + w * 16;   // wave's 16 tokens
    int c0 = cblk * 64;

    const short* Ob = Otm + ((size_t)b * N_TOK + n0) * 64;
    bf16x8 a0 = *(const bf16x8*)(Ob + lr * 64 + 8 * g);
    bf16x8 a1 = *(const bf16x8*)(Ob + lr * 64 + 32 + 8 * g);

    #pragma unroll
    for (int ct = 0; ct < 4; ++ct) {
        int c = c0 + ct * 16 + lr;
        const short* wp = Wu + (size_t)c * 64 + 8 * g;
        bf16x8 b0 = *(const bf16x8*)wp;
        bf16x8 b1 = *(const bf16x8*)(wp + 32);
        f32x4 acc = (f32x4){0.f, 0.f, 0.f, 0.f};
        acc = __builtin_amdgcn_mfma_f32_16x16x32_bf16(a0, b0, acc, 0, 0, 0);
        acc = __builtin_amdgcn_mfma_f32_16x16x32_bf16(a1, b1, acc, 0, 0, 0);
        float bc = bu[c];
        size_t base = ((size_t)b * CIN + c) * N_TOK + n0 + 4 * g;
        float4 xr = *(const float4*)(x + base);
        float4 yo;
        yo.x = acc[0] + bc + xr.x;
        yo.y = acc[1] + bc + xr.y;
        yo.z = acc[2] + bc + xr.z;
        yo.w = acc[3] + bc + xr.w;
        *(float4*)(y + base) = yo;
    }
}

extern "C" void kernel_launch(void* const* d_in, const int* in_sizes, int n_in,
                              void* d_out, int out_size, void* d_ws, size_t ws_size,
                              hipStream_t stream) {
    const float* x  = (const float*)d_in[0];
    const float* wk = (const float*)d_in[1];
    const float* bk = (const float*)d_in[2];
    const float* wq = (const float*)d_in[3];
    const float* bq = (const float*)d_in[4];
    const float* wv = (const float*)d_in[5];
    const float* bv = (const float*)d_in[6];
    const float* wu = (const float*)d_in[7];
    const float* bu = (const float*)d_in[8];
    float* out = (float*)d_out;

    char* ws = (char*)d_ws;
    if (ws_size < (size_t)(9u << 20)) return;
    short* Qt  = (short*)(ws);                       // 2 MB  [B][N][64] bf16
    short* Kt  = (short*)(ws + (2u << 20));          // 2 MB
    short* Vd  = (short*)(ws + (4u << 20));          // 2 MB  [B][64][N] bf16 (permuted cols)
    short* Otm = (short*)(ws + (6u << 20));          // 2 MB  [B][N][64] bf16
    short* Wb  = (short*)(ws + (8u << 20));          // 96 KB [192][256] bf16
    short* Wu  = Wb + 192 * 256;                     // 32 KB [256][64] bf16
    float* bqs = (float*)(Wu + 256 * 64);            // 256 B

    prep_w<<<dim3(64), dim3(256), 0, stream>>>(wq, wk, wv, wu, bq, Wb, Wu, bqs);
    qkv_kernel<<<dim3(1024), dim3(256), 0, stream>>>(x, Wb, bqs, bk, bv, Qt, Kt, Vd);
    attn_kernel<<<dim3(1024), dim3(256), 0, stream>>>(Qt, Kt, Vd, Otm);
    out_kernel<<<dim3(1024), dim3(256), 0, stream>>>(Otm, Wu, bu, x, out);
}

// Round 7
// 66.049 us; speedup vs baseline: 4.1366x; 2.2938x over previous
//
#include <hip/hip_runtime.h>
#include <math.h>

#define N_TOK 4096
#define CIN 256
#define CBN 64
#define LOG2E 1.44269504f

typedef __attribute__((ext_vector_type(8))) short bf16x8;
typedef __attribute__((ext_vector_type(4))) float f32x4;

static __device__ __forceinline__ unsigned short f2bf(float f) {
    union { float f; unsigned u; } v; v.f = f;
    unsigned r = v.u + 0x7fffu + ((v.u >> 16) & 1u);
    return (unsigned short)(r >> 16);
}
static __device__ __forceinline__ unsigned pack2(float a, float b) {
    return (unsigned)f2bf(a) | ((unsigned)f2bf(b) << 16);
}

// ---------------- kernel 1: weight prep ----------------
// Wb bf16 [192][256]: rows 0-63 = wq*log2e, 64-127 = wk, 128-191 = wv.
// Wu bf16 [256][64]. bqs = bq*log2e (fp32).
__global__ __launch_bounds__(256) void prep_w(
        const float* __restrict__ wq, const float* __restrict__ wk,
        const float* __restrict__ wv, const float* __restrict__ wu,
        const float* __restrict__ bq,
        short* __restrict__ Wb, short* __restrict__ Wu, float* __restrict__ bqs) {
    int idx = blockIdx.x * 256 + threadIdx.x;   // 0..16383
    int d = idx >> 8, c = idx & 255;            // w*[d][c]
    Wb[d * 256 + c]         = (short)f2bf(wq[idx] * LOG2E);
    Wb[(64 + d) * 256 + c]  = (short)f2bf(wk[idx]);
    Wb[(128 + d) * 256 + c] = (short)f2bf(wv[idx]);
    Wu[idx] = (short)f2bf(wu[idx]);             // wu already [256][64]
    if (idx < 64) bqs[idx] = bq[idx] * LOG2E;
}

// ---------------- kernel 2: QKV projection (MFMA) ----------------
// Block = 16 tokens. Stage x-tile [16 tok][256 c] -> LDS bf16 (transposed),
// one barrier, then pure MFMA: wave w computes 16-d tile of Q, K and V.
// Q,K token-major [B][N][64]; V d-major [B][64][N] with the verified
// in-32 column permutation col' = 8*((u>>2)&3) + 4*(u>>4) + (u&3).
__global__ __launch_bounds__(256) void qkv_kernel(
        const float* __restrict__ x, const short* __restrict__ Wb,
        const float* __restrict__ bqs, const float* __restrict__ bk, const float* __restrict__ bv,
        short* __restrict__ Qt, short* __restrict__ Kt, short* __restrict__ Vd) {
    int t = threadIdx.x;
    int blk = blockIdx.x;           // 1024 = B(4) * 256 token-tiles
    int b = blk >> 8;
    int n0 = (blk & 255) * 16;

    __shared__ short Xs[16][264];   // [tok][c], 528B rows (16B-aligned)

    {
        int tok4 = t & 3;           // token quad 0..3
        int cb = t >> 2;            // 64 c per pass
        const float* xb = x + (size_t)b * CIN * N_TOK + n0 + tok4 * 4;
        #pragma unroll
        for (int p = 0; p < 4; ++p) {
            int c = p * 64 + cb;
            float4 xv = *(const float4*)(xb + (size_t)c * N_TOK);
            float xs[4] = {xv.x, xv.y, xv.z, xv.w};
            #pragma unroll
            for (int i = 0; i < 4; ++i)
                Xs[tok4 * 4 + i][c] = (short)f2bf(xs[i]);
        }
    }
    __syncthreads();

    int w = t >> 6;         // wave -> d-tile index (0..3)
    int g = (t >> 4) & 3;
    int lr = t & 15;

    f32x4 acc[3];
    #pragma unroll
    for (int m = 0; m < 3; ++m) acc[m] = (f32x4){0.f, 0.f, 0.f, 0.f};
    const short* wbase = Wb + (size_t)(w * 16 + lr) * 256 + 8 * g;
    #pragma unroll
    for (int ks = 0; ks < 8; ++ks) {
        bf16x8 xf = *(const bf16x8*)&Xs[lr][ks * 32 + 8 * g];
        #pragma unroll
        for (int m = 0; m < 3; ++m) {
            bf16x8 wf = *(const bf16x8*)(wbase + (size_t)m * 64 * 256 + ks * 32);
            acc[m] = __builtin_amdgcn_mfma_f32_16x16x32_bf16(wf, xf, acc[m], 0, 0, 0);
        }
    }
    int d0 = w * 16 + 4 * g;
    int tok = n0 + lr;
    float4 bq4 = *(const float4*)(bqs + d0);
    float4 bk4 = *(const float4*)(bk + d0);
    float4 bv4 = *(const float4*)(bv + d0);
    size_t qo = ((size_t)b * N_TOK + tok) * 64 + d0;
    uint2 qp, kp;
    qp.x = pack2(acc[0][0] + bq4.x, acc[0][1] + bq4.y);
    qp.y = pack2(acc[0][2] + bq4.z, acc[0][3] + bq4.w);
    kp.x = pack2(acc[1][0] + bk4.x, acc[1][1] + bk4.y);
    kp.y = pack2(acc[1][2] + bk4.z, acc[1][3] + bk4.w);
    *(uint2*)(Qt + qo) = qp;
    *(uint2*)(Kt + qo) = kp;
    int u = tok & 31;
    int vcol = (tok & ~31) + 8 * ((u >> 2) & 3) + 4 * (u >> 4) + (u & 3);
    float bvr[4] = {bv4.x, bv4.y, bv4.z, bv4.w};
    #pragma unroll
    for (int r = 0; r < 4; ++r)
        Vd[((size_t)b * 64 + d0 + r) * N_TOK + vcol] = (short)f2bf(acc[2][r] + bvr[r]);
}

// ---------------- kernel 3: attention, LDS-staged K/V ----------
// 256 blocks x 1024 thr: 16 waves = 4 q-tiles x 4 key-splits.
// Per iter: stage next 64-key K/V tiles (one per split) via global_load_lds
// into double-buffered LDS; compute current tile; one barrier.
// XOR chunk-swizzle (chunk ^= row&7) applied to the per-lane GLOBAL source
// (LDS dest linear, rule: both-sides-or-neither) and to the ds_read side.
// In-block 4-way split merge through the dead staging LDS at the end.
__global__ __launch_bounds__(1024, 4) void attn_kernel(
        const short* __restrict__ Qt, const short* __restrict__ Kt,
        const short* __restrict__ Vsw, short* __restrict__ Otm) {
    int t = threadIdx.x;
    int w = t >> 6;          // wave 0..15
    int qt_l = w >> 2;       // local q-tile 0..3
    int sp = w & 3;          // key-split 0..3
    int g = (t >> 4) & 3;
    int lr = t & 15;
    int l = t & 63;

    int bid = blockIdx.x;
    int blk = ((bid & 7) << 5) | (bid >> 3);   // XCD swizzle, bijective (256=8*32)
    int qtg = blk * 4 + qt_l;                  // global q-tile 0..1023
    int b = qtg >> 8;
    int q0 = (qtg & 255) * 16;

    const short* Qb = Qt + (size_t)b * N_TOK * 64;
    const short* Kb = Kt + (size_t)b * N_TOK * 64;
    const short* Vb = Vsw + (size_t)b * 64 * N_TOK;

    __shared__ __align__(16) char LB[4][2][16384];  // [split][buf][K 8KB | V 8KB]
    __shared__ float Ml[16][16];                    // [wave][q] l partials

    bf16x8 qf0 = *(const bf16x8*)(Qb + (q0 + lr) * 64 + 8 * g);
    bf16x8 qf1 = *(const bf16x8*)(Qb + (q0 + lr) * 64 + 32 + 8 * g);

    f32x4 o[4];
    #pragma unroll
    for (int mt = 0; mt < 4; ++mt) o[mt] = (f32x4){0.f, 0.f, 0.f, 0.f};
    float lacc = 0.f;

    // staging lane geometry: seg = 1KB = 8 rows x 8 chunks(16B).
    // lane l -> row-in-seg rr = l>>3, chunk c = l&7; swizzled source chunk = c ^ rr
    // (row&7 == rr for all segs since seg*8 = 0 mod 8).
    int rr = l >> 3;
    int cx8 = ((l & 7) ^ rr) * 8;   // source offset in shorts within row

    auto STAGE = [&](int kt, int buf) {
        int k0 = sp * 1024 + kt * 64;
        char* dst0 = &LB[sp][buf][0];
        #pragma unroll
        for (int j = 0; j < 4; ++j) {
            int seg = qt_l * 4 + j;            // this wave's 4 segments (of 16)
            const short* src;
            if (seg < 8)   // K rows = keys
                src = Kb + (size_t)(k0 + seg * 8 + rr) * 64 + cx8;
            else           // V rows = d
                src = Vb + (size_t)((seg - 8) * 8 + rr) * N_TOK + k0 + cx8;
            __builtin_amdgcn_global_load_lds(
                (const __attribute__((address_space(1))) void*)src,
                (__attribute__((address_space(3))) void*)(dst0 + seg * 1024),
                16, 0, 0);
        }
    };

    STAGE(0, 0);
    __syncthreads();

    int xk = lr & 7;
    int cA = (g ^ xk) << 4;          // swizzled chunk byte offset (read side)
    int cur = 0;
    for (int kt = 0; kt < 16; ++kt) {
        if (kt < 15) STAGE(kt + 1, cur ^ 1);
        const char* KB_ = &LB[sp][cur][0];
        const char* VB_ = KB_ + 8192;
        // ---- S^T = K·Q^T : row = key (4g+r), col = query (lr) ----
        f32x4 s[4];
        #pragma unroll
        for (int nt = 0; nt < 4; ++nt) {
            const char* rp = KB_ + (nt * 16 + lr) * 128;
            bf16x8 kf0 = *(const bf16x8*)(rp + cA);          // d [8g,8g+8)
            bf16x8 kf1 = *(const bf16x8*)(rp + (cA ^ 64));   // d [32+8g,..)
            f32x4 z = (f32x4){0.f, 0.f, 0.f, 0.f};
            z = __builtin_amdgcn_mfma_f32_16x16x32_bf16(kf0, qf0, z, 0, 0, 0);
            s[nt] = __builtin_amdgcn_mfma_f32_16x16x32_bf16(kf1, qf1, z, 0, 0, 0);
        }
        // ---- p = 2^s ; in-lane l accumulation ----
        #pragma unroll
        for (int nt = 0; nt < 4; ++nt)
            #pragma unroll
            for (int r = 0; r < 4; ++r) {
                float p = __builtin_amdgcn_exp2f(s[nt][r]);
                s[nt][r] = p;
                lacc += p;
            }
        // ---- pack P to bf16 B-fragments in-register (slot-consistent) ----
        bf16x8 bp0, bp1;
        #pragma unroll
        for (int e = 0; e < 8; ++e) {
            bp0[e] = (short)f2bf(s[e >> 2][e & 3]);
            bp1[e] = (short)f2bf(s[2 + (e >> 2)][e & 3]);
        }
        // ---- O^T[d][q] += V·P (V pre-permuted to the same slot order) ----
        #pragma unroll
        for (int mt = 0; mt < 4; ++mt) {
            const char* rp = VB_ + (mt * 16 + lr) * 128;
            bf16x8 av0 = *(const bf16x8*)(rp + cA);          // keys [0,32)
            bf16x8 av1 = *(const bf16x8*)(rp + (cA ^ 64));   // keys [32,64)
            o[mt] = __builtin_amdgcn_mfma_f32_16x16x32_bf16(av0, bp0, o[mt], 0, 0, 0);
            o[mt] = __builtin_amdgcn_mfma_f32_16x16x32_bf16(av1, bp1, o[mt], 0, 0, 0);
        }
        __syncthreads();   // staging for kt+1 drained; buf[cur] reads done
        cur ^= 1;
    }
    // ---- l: reduce across the 4 lane-groups ----
    lacc += __shfl_xor(lacc, 16);
    lacc += __shfl_xor(lacc, 32);
    // ---- partials into (dead) staging LDS, then in-block merge ----
    float* OmL = (float*)&LB[0][0][0];   // [16 wave][16 q][64 d] fp32 = 64 KB
    #pragma unroll
    for (int mt = 0; mt < 4; ++mt)
        *(f32x4*)(OmL + (w * 16 + lr) * 64 + mt * 16 + 4 * g) = o[mt];
    Ml[w][lr] = lacc;
    __syncthreads();
    {
        int qt2 = t >> 8, q = (t >> 4) & 15, dq = t & 15;
        float a0 = 0.f, a1 = 0.f, a2 = 0.f, a3 = 0.f, lsum = 0.f;
        #pragma unroll
        for (int s2 = 0; s2 < 4; ++s2) {
            const float* pp = OmL + ((qt2 * 4 + s2) * 16 + q) * 64 + dq * 4;
            float4 v = *(const float4*)pp;
            a0 += v.x; a1 += v.y; a2 += v.z; a3 += v.w;
            lsum += Ml[qt2 * 4 + s2][q];
        }
        float inv = 1.f / lsum;
        int qtg2 = blk * 4 + qt2;
        int b2 = qtg2 >> 8;
        int tok = (qtg2 & 255) * 16 + q;
        uint2 ow;
        ow.x = pack2(a0 * inv, a1 * inv);
        ow.y = pack2(a2 * inv, a3 * inv);
        *(uint2*)(Otm + ((size_t)b2 * N_TOK + tok) * 64 + dq * 4) = ow;
    }
}

// ---------------- kernel 4: up-projection + bias + residual (MFMA) --------
__global__ __launch_bounds__(256) void out_kernel(
        const short* __restrict__ Otm, const short* __restrict__ Wu,
        const float* __restrict__ bu, const float* __restrict__ x,
        float* __restrict__ y) {
    int t = threadIdx.x;
    int w = t >> 6, g = (t >> 4) & 3, lr = t & 15;
    int blk = blockIdx.x;          // 1024 = B(4) * 64 tok-tiles * 4 c-blocks
    int b = blk >> 8;
    int rem = blk & 255;
    int nblk = rem >> 2, cblk = rem & 3;
    int n0 = nblk * 64 + w * 16;
    int c0 = cblk * 64;

    const short* Ob = Otm + ((size_t)b * N_TOK + n0) * 64;
    bf16x8 a0 = *(const bf16x8*)(Ob + lr * 64 + 8 * g);
    bf16x8 a1 = *(const bf16x8*)(Ob + lr * 64 + 32 + 8 * g);

    #pragma unroll
    for (int ct = 0; ct < 4; ++ct) {
        int c = c0 + ct * 16 + lr;
        const short* wp = Wu + (size_t)c * 64 + 8 * g;
        bf16x8 b0 = *(const bf16x8*)wp;
        bf16x8 b1 = *(const bf16x8*)(wp + 32);
        f32x4 acc = (f32x4){0.f, 0.f, 0.f, 0.f};
        acc = __builtin_amdgcn_mfma_f32_16x16x32_bf16(a0, b0, acc, 0, 0, 0);
        acc = __builtin_amdgcn_mfma_f32_16x16x32_bf16(a1, b1, acc, 0, 0, 0);
        float bc = bu[c];
        size_t base = ((size_t)b * CIN + c) * N_TOK + n0 + 4 * g;
        float4 xr = *(const float4*)(x + base);
        float4 yo;
        yo.x = acc[0] + bc + xr.x;
        yo.y = acc[1] + bc + xr.y;
        yo.z = acc[2] + bc + xr.z;
        yo.w = acc[3] + bc + xr.w;
        *(float4*)(y + base) = yo;
    }
}

extern "C" void kernel_launch(void* const* d_in, const int* in_sizes, int n_in,
                              void* d_out, int out_size, void* d_ws, size_t ws_size,
                              hipStream_t stream) {
    const float* x  = (const float*)d_in[0];
    const float* wk = (const float*)d_in[1];
    const float* bk = (const float*)d_in[2];
    const float* wq = (const float*)d_in[3];
    const float* bq = (const float*)d_in[4];
    const float* wv = (const float*)d_in[5];
    const float* bv = (const float*)d_in[6];
    const float* wu = (const float*)d_in[7];
    const float* bu = (const float*)d_in[8];
    float* out = (float*)d_out;

    char* ws = (char*)d_ws;
    if (ws_size < (size_t)(9u << 20)) return;
    short* Qt  = (short*)(ws);                       // 2 MB  [B][N][64] bf16
    short* Kt  = (short*)(ws + (2u << 20));          // 2 MB
    short* Vd  = (short*)(ws + (4u << 20));          // 2 MB  [B][64][N] bf16 (permuted cols)
    short* Otm = (short*)(ws + (6u << 20));          // 2 MB  [B][N][64] bf16
    short* Wb  = (short*)(ws + (8u << 20));          // 96 KB [192][256] bf16
    short* Wu  = Wb + 192 * 256;                     // 32 KB [256][64] bf16
    float* bqs = (float*)(Wu + 256 * 64);            // 256 B

    prep_w<<<dim3(64), dim3(256), 0, stream>>>(wq, wk, wv, wu, bq, Wb, Wu, bqs);
    qkv_kernel<<<dim3(1024), dim3(256), 0, stream>>>(x, Wb, bqs, bk, bv, Qt, Kt, Vd);
    attn_kernel<<<dim3(256), dim3(1024), 0, stream>>>(Qt, Kt, Vd, Otm);
    out_kernel<<<dim3(1024), dim3(256), 0, stream>>>(Otm, Wu, bu, x, out);
}

// Round 8
// 61.794 us; speedup vs baseline: 4.4215x; 1.0689x over previous
//
#include <hip/hip_runtime.h>
#include <math.h>

#define N_TOK 4096
#define CIN 256
#define CBN 64
#define LOG2E 1.44269504f

typedef __attribute__((ext_vector_type(8))) short bf16x8;
typedef __attribute__((ext_vector_type(4))) float f32x4;

static __device__ __forceinline__ unsigned short f2bf(float f) {
    union { float f; unsigned u; } v; v.f = f;
    unsigned r = v.u + 0x7fffu + ((v.u >> 16) & 1u);
    return (unsigned short)(r >> 16);
}
static __device__ __forceinline__ unsigned pack2(float a, float b) {
    return (unsigned)f2bf(a) | ((unsigned)f2bf(b) << 16);
}

// ---------------- kernel 1: weight prep ----------------
// Wb bf16 [192][256]: rows 0-63 = wq*log2e, 64-127 = wk, 128-191 = wv.
// Wu bf16 [256][64]. bqs = bq*log2e (fp32).
__global__ __launch_bounds__(256) void prep_w(
        const float* __restrict__ wq, const float* __restrict__ wk,
        const float* __restrict__ wv, const float* __restrict__ wu,
        const float* __restrict__ bq,
        short* __restrict__ Wb, short* __restrict__ Wu, float* __restrict__ bqs) {
    int idx = blockIdx.x * 256 + threadIdx.x;   // 0..16383
    int d = idx >> 8, c = idx & 255;            // w*[d][c]
    Wb[d * 256 + c]         = (short)f2bf(wq[idx] * LOG2E);
    Wb[(64 + d) * 256 + c]  = (short)f2bf(wk[idx]);
    Wb[(128 + d) * 256 + c] = (short)f2bf(wv[idx]);
    Wu[idx] = (short)f2bf(wu[idx]);             // wu already [256][64]
    if (idx < 64) bqs[idx] = bq[idx] * LOG2E;
}

// ---------------- kernel 2: QKV projection (MFMA) ----------------
// Block = 32 tokens (full 128B cache lines on x). Stage x-tile -> LDS bf16,
// one barrier, then MFMA: wave w computes 16-d tile for 2 token-subtiles.
// Q,K token-major [B][N][64]; V d-major [B][64][N] with the verified
// in-32 column permutation col' = 8*((u>>2)&3) + 4*(u>>4) + (u&3).
__global__ __launch_bounds__(256) void qkv_kernel(
        const float* __restrict__ x, const short* __restrict__ Wb,
        const float* __restrict__ bqs, const float* __restrict__ bk, const float* __restrict__ bv,
        short* __restrict__ Qt, short* __restrict__ Kt, short* __restrict__ Vd) {
    int t = threadIdx.x;
    int blk = blockIdx.x;           // 512 = B(4) * 128 token-tiles
    int b = blk >> 7;
    int n0 = (blk & 127) * 32;

    __shared__ short Xs[32][264];   // [tok][c], 528B rows (16B-aligned)

    {
        int tok4 = t & 7;           // 8 token-quads = 32 tokens
        int cb = t >> 3;            // 32 c per pass
        const float* xb = x + (size_t)b * CIN * N_TOK + n0 + tok4 * 4;
        #pragma unroll
        for (int p = 0; p < 8; ++p) {
            int c = p * 32 + cb;
            float4 xv = *(const float4*)(xb + (size_t)c * N_TOK);
            float xs[4] = {xv.x, xv.y, xv.z, xv.w};
            #pragma unroll
            for (int i = 0; i < 4; ++i)
                Xs[tok4 * 4 + i][c] = (short)f2bf(xs[i]);
        }
    }
    __syncthreads();

    int w = t >> 6;         // wave -> d-tile index (0..3)
    int g = (t >> 4) & 3;
    int lr = t & 15;

    f32x4 acc[3][2];
    #pragma unroll
    for (int m = 0; m < 3; ++m)
        #pragma unroll
        for (int st = 0; st < 2; ++st) acc[m][st] = (f32x4){0.f, 0.f, 0.f, 0.f};
    const short* wbase = Wb + (size_t)(w * 16 + lr) * 256 + 8 * g;
    #pragma unroll
    for (int ks = 0; ks < 8; ++ks) {
        bf16x8 xf0 = *(const bf16x8*)&Xs[lr][ks * 32 + 8 * g];
        bf16x8 xf1 = *(const bf16x8*)&Xs[16 + lr][ks * 32 + 8 * g];
        #pragma unroll
        for (int m = 0; m < 3; ++m) {
            bf16x8 wf = *(const bf16x8*)(wbase + (size_t)m * 64 * 256 + ks * 32);
            acc[m][0] = __builtin_amdgcn_mfma_f32_16x16x32_bf16(wf, xf0, acc[m][0], 0, 0, 0);
            acc[m][1] = __builtin_amdgcn_mfma_f32_16x16x32_bf16(wf, xf1, acc[m][1], 0, 0, 0);
        }
    }
    int d0 = w * 16 + 4 * g;
    float4 bq4 = *(const float4*)(bqs + d0);
    float4 bk4 = *(const float4*)(bk + d0);
    float4 bv4 = *(const float4*)(bv + d0);
    float bvr[4] = {bv4.x, bv4.y, bv4.z, bv4.w};
    #pragma unroll
    for (int st = 0; st < 2; ++st) {
        int tok = n0 + st * 16 + lr;
        size_t qo = ((size_t)b * N_TOK + tok) * 64 + d0;
        uint2 qp, kp;
        qp.x = pack2(acc[0][st][0] + bq4.x, acc[0][st][1] + bq4.y);
        qp.y = pack2(acc[0][st][2] + bq4.z, acc[0][st][3] + bq4.w);
        kp.x = pack2(acc[1][st][0] + bk4.x, acc[1][st][1] + bk4.y);
        kp.y = pack2(acc[1][st][2] + bk4.z, acc[1][st][3] + bk4.w);
        *(uint2*)(Qt + qo) = qp;
        *(uint2*)(Kt + qo) = kp;
        int u = tok & 31;
        int vcol = (tok & ~31) + 8 * ((u >> 2) & 3) + 4 * (u >> 4) + (u & 3);
        #pragma unroll
        for (int r = 0; r < 4; ++r)
            Vd[((size_t)b * 64 + d0 + r) * N_TOK + vcol] = (short)f2bf(acc[2][st][r] + bvr[r]);
    }
}

// ---------------- kernel 3: attention, LDS-staged K/V ----------
// 256 blocks x 1024 thr: 16 waves = 2 wave-q x 8 key-splits; each wave owns
// 2 q-tiles (32 queries) so every K/V LDS fragment feeds 2x MFMA.
// 32-key tiles, double-buffered: K 4KB (32 rows x 128B, chunk^=(row&7)),
// V 4KB (64 rows x 64B, chunk^=(row&3)); swizzle applied to the GLOBAL
// source (LDS dest linear) and to the ds_read side (involution, rule 21).
// In-block 8-way split merge through the dead 128KB staging LDS at the end.
__global__ __launch_bounds__(1024, 4) void attn_kernel(
        const short* __restrict__ Qt, const short* __restrict__ Kt,
        const short* __restrict__ Vsw, short* __restrict__ Otm) {
    int t = threadIdx.x;
    int w = t >> 6;          // wave 0..15
    int wq = w >> 3;         // 0..1: q-pair selector; also K(0)/V(1) stager
    int sp = w & 7;          // key-split 0..7
    int g = (t >> 4) & 3;
    int lr = t & 15;
    int l = t & 63;

    int bid = blockIdx.x;
    int blk = ((bid & 7) << 5) | (bid >> 3);   // XCD swizzle, bijective (256=8*32)
    int b = blk >> 6;                           // 64 blocks per batch
    int q0 = (blk & 63) * 64;                   // 64 queries per block

    const short* Qb = Qt + (size_t)b * N_TOK * 64;
    const short* Kb = Kt + (size_t)b * N_TOK * 64;
    const short* Vb = Vsw + (size_t)b * 64 * N_TOK;

    __shared__ __align__(16) char LB[8][2][8192];  // [split][buf][K 4KB | V 4KB]
    __shared__ float Ml[32][16];                   // [qt*8+sp][q] l partials

    // Q fragments for this wave's two q-tiles (qt = wq*2 + j)
    bf16x8 qf[2][2];
    #pragma unroll
    for (int j = 0; j < 2; ++j) {
        const short* qp = Qb + (q0 + (wq * 2 + j) * 16 + lr) * 64 + 8 * g;
        qf[j][0] = *(const bf16x8*)qp;
        qf[j][1] = *(const bf16x8*)(qp + 32);
    }

    f32x4 o[2][4];
    #pragma unroll
    for (int j = 0; j < 2; ++j)
        #pragma unroll
        for (int mt = 0; mt < 4; ++mt) o[j][mt] = (f32x4){0.f, 0.f, 0.f, 0.f};
    float la0 = 0.f, la1 = 0.f;

    // staging lane geometry
    int krow = l >> 3;                    // K: row-in-8 per call
    int kchk = ((l & 7) ^ krow) * 8;      // K source chunk (shorts)
    int vrow = l >> 2;                    // V: row-in-16 per call
    int vchk = ((l & 3) ^ (vrow & 3)) * 8;

    auto STAGE = [&](int kt, int buf) {
        int k0s = sp * 512 + kt * 32;
        char* dst0 = &LB[sp][buf][0];
        if (wq == 0) {      // K tile: 32 rows x 128B
            #pragma unroll
            for (int j = 0; j < 4; ++j) {
                const short* src = Kb + (size_t)(k0s + j * 8 + krow) * 64 + kchk;
                __builtin_amdgcn_global_load_lds(
                    (const __attribute__((address_space(1))) void*)src,
                    (__attribute__((address_space(3))) void*)(dst0 + j * 1024),
                    16, 0, 0);
            }
        } else {            // V tile: 64 rows x 64B
            #pragma unroll
            for (int j = 0; j < 4; ++j) {
                const short* src = Vb + (size_t)(j * 16 + vrow) * N_TOK + k0s + vchk;
                __builtin_amdgcn_global_load_lds(
                    (const __attribute__((address_space(1))) void*)src,
                    (__attribute__((address_space(3))) void*)(dst0 + 4096 + j * 1024),
                    16, 0, 0);
            }
        }
    };

    STAGE(0, 0);
    __syncthreads();

    int cK = (g ^ (lr & 7)) << 4;    // K read chunk byte offset (swizzled)
    int cV = (g ^ (lr & 3)) << 4;    // V read chunk byte offset (swizzled)
    int cur = 0;
    for (int kt = 0; kt < 16; ++kt) {
        if (kt < 15) STAGE(kt + 1, cur ^ 1);
        const char* KB_ = &LB[sp][cur][0];
        const char* VB_ = KB_ + 4096;
        // ---- S^T = K·Q^T : row = key (16nt+4g+r), col = query (lr) ----
        f32x4 s[2][2];
        #pragma unroll
        for (int nt = 0; nt < 2; ++nt) {
            const char* rp = KB_ + (nt * 16 + lr) * 128;
            bf16x8 kf0 = *(const bf16x8*)(rp + cK);
            bf16x8 kf1 = *(const bf16x8*)(rp + (cK ^ 64));
            #pragma unroll
            for (int j = 0; j < 2; ++j) {
                f32x4 z = (f32x4){0.f, 0.f, 0.f, 0.f};
                z = __builtin_amdgcn_mfma_f32_16x16x32_bf16(kf0, qf[j][0], z, 0, 0, 0);
                s[j][nt] = __builtin_amdgcn_mfma_f32_16x16x32_bf16(kf1, qf[j][1], z, 0, 0, 0);
            }
        }
        // ---- p = 2^s ; in-lane l accumulation ----
        #pragma unroll
        for (int nt = 0; nt < 2; ++nt)
            #pragma unroll
            for (int r = 0; r < 4; ++r) {
                float p0 = __builtin_amdgcn_exp2f(s[0][nt][r]);
                float p1 = __builtin_amdgcn_exp2f(s[1][nt][r]);
                s[0][nt][r] = p0; la0 += p0;
                s[1][nt][r] = p1; la1 += p1;
            }
        // ---- pack P to bf16 B-fragments in-register (slot-consistent) ----
        bf16x8 bp[2];
        #pragma unroll
        for (int e = 0; e < 8; ++e) {
            bp[0][e] = (short)f2bf(s[0][e >> 2][e & 3]);
            bp[1][e] = (short)f2bf(s[1][e >> 2][e & 3]);
        }
        // ---- O^T[d][q] += V·P (V pre-permuted to the same slot order) ----
        #pragma unroll
        for (int mt = 0; mt < 4; ++mt) {
            bf16x8 av = *(const bf16x8*)(VB_ + (mt * 16 + lr) * 64 + cV);
            o[0][mt] = __builtin_amdgcn_mfma_f32_16x16x32_bf16(av, bp[0], o[0][mt], 0, 0, 0);
            o[1][mt] = __builtin_amdgcn_mfma_f32_16x16x32_bf16(av, bp[1], o[1][mt], 0, 0, 0);
        }
        __syncthreads();   // staging for kt+1 drained; buf[cur] reads done
        cur ^= 1;
    }
    // ---- l: reduce across the 4 lane-groups ----
    la0 += __shfl_xor(la0, 16); la0 += __shfl_xor(la0, 32);
    la1 += __shfl_xor(la1, 16); la1 += __shfl_xor(la1, 32);
    // ---- partials into (dead) staging LDS, then in-block merge ----
    float* OmL = (float*)&LB[0][0][0];   // [4 qt][8 sp][16 q][64 d] = 128 KB
    #pragma unroll
    for (int j = 0; j < 2; ++j) {
        int qt = wq * 2 + j;
        #pragma unroll
        for (int mt = 0; mt < 4; ++mt)
            *(f32x4*)(OmL + ((qt * 8 + sp) * 16 + lr) * 64 + mt * 16 + 4 * g) = o[j][mt];
        Ml[qt * 8 + sp][lr] = j == 0 ? la0 : la1;
    }
    __syncthreads();
    {
        int qt2 = t >> 8, q = (t >> 4) & 15, dq = t & 15;
        float a0 = 0.f, a1 = 0.f, a2 = 0.f, a3 = 0.f, lsum = 0.f;
        #pragma unroll
        for (int s2 = 0; s2 < 8; ++s2) {
            const float* pp = OmL + ((qt2 * 8 + s2) * 16 + q) * 64 + dq * 4;
            float4 v = *(const float4*)pp;
            a0 += v.x; a1 += v.y; a2 += v.z; a3 += v.w;
            lsum += Ml[qt2 * 8 + s2][q];
        }
        float inv = 1.f / lsum;
        int tok = q0 + qt2 * 16 + q;
        uint2 ow;
        ow.x = pack2(a0 * inv, a1 * inv);
        ow.y = pack2(a2 * inv, a3 * inv);
        *(uint2*)(Otm + ((size_t)b * N_TOK + tok) * 64 + dq * 4) = ow;
    }
}

// ---------------- kernel 4: up-projection + bias + residual (MFMA) --------
__global__ __launch_bounds__(256) void out_kernel(
        const short* __restrict__ Otm, const short* __restrict__ Wu,
        const float* __restrict__ bu, const float* __restrict__ x,
        float* __restrict__ y) {
    int t = threadIdx.x;
    int w = t >> 6, g = (t >> 4) & 3, lr = t & 15;
    int blk = blockIdx.x;          // 1024 = B(4) * 64 tok-tiles * 4 c-blocks
    int b = blk >> 8;
    int rem = blk & 255;
    int nblk = rem >> 2, cblk = rem & 3;
    int n0 = nblk * 64 + w * 16;
    int c0 = cblk * 64;

    const short* Ob = Otm + ((size_t)b * N_TOK + n0) * 64;
    bf16x8 a0 = *(const bf16x8*)(Ob + lr * 64 + 8 * g);
    bf16x8 a1 = *(const bf16x8*)(Ob + lr * 64 + 32 + 8 * g);

    #pragma unroll
    for (int ct = 0; ct < 4; ++ct) {
        int c = c0 + ct * 16 + lr;
        const short* wp = Wu + (size_t)c * 64 + 8 * g;
        bf16x8 b0 = *(const bf16x8*)wp;
        bf16x8 b1 = *(const bf16x8*)(wp + 32);
        f32x4 acc = (f32x4){0.f, 0.f, 0.f, 0.f};
        acc = __builtin_amdgcn_mfma_f32_16x16x32_bf16(a0, b0, acc, 0, 0, 0);
        acc = __builtin_amdgcn_mfma_f32_16x16x32_bf16(a1, b1, acc, 0, 0, 0);
        float bc = bu[c];
        size_t base = ((size_t)b * CIN + c) * N_TOK + n0 + 4 * g;
        float4 xr = *(const float4*)(x + base);
        float4 yo;
        yo.x = acc[0] + bc + xr.x;
        yo.y = acc[1] + bc + xr.y;
        yo.z = acc[2] + bc + xr.z;
        yo.w = acc[3] + bc + xr.w;
        *(float4*)(y + base) = yo;
    }
}

extern "C" void kernel_launch(void* const* d_in, const int* in_sizes, int n_in,
                              void* d_out, int out_size, void* d_ws, size_t ws_size,
                              hipStream_t stream) {
    const float* x  = (const float*)d_in[0];
    const float* wk = (const float*)d_in[1];
    const float* bk = (const float*)d_in[2];
    const float* wq = (const float*)d_in[3];
    const float* bq = (const float*)d_in[4];
    const float* wv = (const float*)d_in[5];
    const float* bv = (const float*)d_in[6];
    const float* wu = (const float*)d_in[7];
    const float* bu = (const float*)d_in[8];
    float* out = (float*)d_out;

    char* ws = (char*)d_ws;
    if (ws_size < (size_t)(9u << 20)) return;
    short* Qt  = (short*)(ws);                       // 2 MB  [B][N][64] bf16
    short* Kt  = (short*)(ws + (2u << 20));          // 2 MB
    short* Vd  = (short*)(ws + (4u << 20));          // 2 MB  [B][64][N] bf16 (permuted cols)
    short* Otm = (short*)(ws + (6u << 20));          // 2 MB  [B][N][64] bf16
    short* Wb  = (short*)(ws + (8u << 20));          // 96 KB [192][256] bf16
    short* Wu  = Wb + 192 * 256;                     // 32 KB [256][64] bf16
    float* bqs = (float*)(Wu + 256 * 64);            // 256 B

    prep_w<<<dim3(64), dim3(256), 0, stream>>>(wq, wk, wv, wu, bq, Wb, Wu, bqs);
    qkv_kernel<<<dim3(512), dim3(256), 0, stream>>>(x, Wb, bqs, bk, bv, Qt, Kt, Vd);
    attn_kernel<<<dim3(256), dim3(1024), 0, stream>>>(Qt, Kt, Vd, Otm);
    out_kernel<<<dim3(1024), dim3(256), 0, stream>>>(Otm, Wu, bu, x, out);
}

// Round 9
// 58.778 us; speedup vs baseline: 4.6483x; 1.0513x over previous
//
#include <hip/hip_runtime.h>
#include <hip/hip_bf16.h>
#include <math.h>

#define N_TOK 4096
#define CIN 256
#define CBN 64
#define LOG2E 1.44269504f

typedef __attribute__((ext_vector_type(8))) short bf16x8;
typedef __attribute__((ext_vector_type(4))) float f32x4;

static __device__ __forceinline__ unsigned short f2bf(float f) {
    union { float f; unsigned u; } v; v.f = f;
    unsigned r = v.u + 0x7fffu + ((v.u >> 16) & 1u);
    return (unsigned short)(r >> 16);
}
// pair-pack via v_cvt_pk_bf16_f32 (RNE, same as f2bf)
static __device__ __forceinline__ unsigned pack2(float a, float b) {
    float2 t2; t2.x = a; t2.y = b;
    __hip_bfloat162 h = __float22bfloat162_rn(t2);
    union { __hip_bfloat162 h; unsigned u; } cv; cv.h = h;
    return cv.u;
}

// ---------------- kernel 1: weight prep ----------------
// Wb bf16 [192][256]: rows 0-63 = wq*log2e, 64-127 = wk, 128-191 = wv.
// Wu bf16 [256][64]. bqs = bq*log2e (fp32).
__global__ __launch_bounds__(256) void prep_w(
        const float* __restrict__ wq, const float* __restrict__ wk,
        const float* __restrict__ wv, const float* __restrict__ wu,
        const float* __restrict__ bq,
        short* __restrict__ Wb, short* __restrict__ Wu, float* __restrict__ bqs) {
    int idx = blockIdx.x * 256 + threadIdx.x;   // 0..16383
    int d = idx >> 8, c = idx & 255;            // w*[d][c]
    Wb[d * 256 + c]         = (short)f2bf(wq[idx] * LOG2E);
    Wb[(64 + d) * 256 + c]  = (short)f2bf(wk[idx]);
    Wb[(128 + d) * 256 + c] = (short)f2bf(wv[idx]);
    Wu[idx] = (short)f2bf(wu[idx]);             // wu already [256][64]
    if (idx < 64) bqs[idx] = bq[idx] * LOG2E;
}

// ---------------- kernel 2: QKV projection (MFMA) ----------------
// Block = 32 tokens. Stage x-tile -> LDS bf16, one barrier, then MFMA:
// wave w computes 16-d tile for 2 token-subtiles.
// Q,K token-major [B][N][64]; V d-major [B][64][N] with the verified
// in-32 column permutation col' = 8*((u>>2)&3) + 4*(u>>4) + (u&3).
__global__ __launch_bounds__(256) void qkv_kernel(
        const float* __restrict__ x, const short* __restrict__ Wb,
        const float* __restrict__ bqs, const float* __restrict__ bk, const float* __restrict__ bv,
        short* __restrict__ Qt, short* __restrict__ Kt, short* __restrict__ Vd) {
    int t = threadIdx.x;
    int blk = blockIdx.x;           // 512 = B(4) * 128 token-tiles
    int b = blk >> 7;
    int n0 = (blk & 127) * 32;

    __shared__ short Xs[32][264];   // [tok][c], 528B rows (16B-aligned)

    {
        int tok4 = t & 7;           // 8 token-quads = 32 tokens
        int cb = t >> 3;            // 32 c per pass
        const float* xb = x + (size_t)b * CIN * N_TOK + n0 + tok4 * 4;
        #pragma unroll
        for (int p = 0; p < 8; ++p) {
            int c = p * 32 + cb;
            float4 xv = *(const float4*)(xb + (size_t)c * N_TOK);
            float xs[4] = {xv.x, xv.y, xv.z, xv.w};
            #pragma unroll
            for (int i = 0; i < 4; ++i)
                Xs[tok4 * 4 + i][c] = (short)f2bf(xs[i]);
        }
    }
    __syncthreads();

    int w = t >> 6;         // wave -> d-tile index (0..3)
    int g = (t >> 4) & 3;
    int lr = t & 15;

    f32x4 acc[3][2];
    #pragma unroll
    for (int m = 0; m < 3; ++m)
        #pragma unroll
        for (int st = 0; st < 2; ++st) acc[m][st] = (f32x4){0.f, 0.f, 0.f, 0.f};
    const short* wbase = Wb + (size_t)(w * 16 + lr) * 256 + 8 * g;
    #pragma unroll
    for (int ks = 0; ks < 8; ++ks) {
        bf16x8 xf0 = *(const bf16x8*)&Xs[lr][ks * 32 + 8 * g];
        bf16x8 xf1 = *(const bf16x8*)&Xs[16 + lr][ks * 32 + 8 * g];
        #pragma unroll
        for (int m = 0; m < 3; ++m) {
            bf16x8 wf = *(const bf16x8*)(wbase + (size_t)m * 64 * 256 + ks * 32);
            acc[m][0] = __builtin_amdgcn_mfma_f32_16x16x32_bf16(wf, xf0, acc[m][0], 0, 0, 0);
            acc[m][1] = __builtin_amdgcn_mfma_f32_16x16x32_bf16(wf, xf1, acc[m][1], 0, 0, 0);
        }
    }
    int d0 = w * 16 + 4 * g;
    float4 bq4 = *(const float4*)(bqs + d0);
    float4 bk4 = *(const float4*)(bk + d0);
    float4 bv4 = *(const float4*)(bv + d0);
    float bvr[4] = {bv4.x, bv4.y, bv4.z, bv4.w};
    #pragma unroll
    for (int st = 0; st < 2; ++st) {
        int tok = n0 + st * 16 + lr;
        size_t qo = ((size_t)b * N_TOK + tok) * 64 + d0;
        uint2 qp, kp;
        qp.x = pack2(acc[0][st][0] + bq4.x, acc[0][st][1] + bq4.y);
        qp.y = pack2(acc[0][st][2] + bq4.z, acc[0][st][3] + bq4.w);
        kp.x = pack2(acc[1][st][0] + bk4.x, acc[1][st][1] + bk4.y);
        kp.y = pack2(acc[1][st][2] + bk4.z, acc[1][st][3] + bk4.w);
        *(uint2*)(Qt + qo) = qp;
        *(uint2*)(Kt + qo) = kp;
        int u = tok & 31;
        int vcol = (tok & ~31) + 8 * ((u >> 2) & 3) + 4 * (u >> 4) + (u & 3);
        #pragma unroll
        for (int r = 0; r < 4; ++r)
            Vd[((size_t)b * 64 + d0 + r) * N_TOK + vcol] = (short)f2bf(acc[2][st][r] + bvr[r]);
    }
}

// ---------------- kernel 3: fused attention + up-projection ----------
// 256 blocks x 1024 thr: 16 waves = 2 wave-q x 8 key-splits; each wave owns
// 2 q-tiles (32 queries). 32-key double-buffered LDS tiles via
// global_load_lds with XOR chunk-swizzle on the GLOBAL source + ds_read side.
// After the in-block 8-way merge, O (64 tok x 64 d bf16) stays in LDS
// (XOR-swizzled) and phase B does the wu up-projection + bias + residual.
__global__ __launch_bounds__(1024, 4) void attn_out_kernel(
        const short* __restrict__ Qt, const short* __restrict__ Kt,
        const short* __restrict__ Vsw, const short* __restrict__ Wu,
        const float* __restrict__ bu, const float* __restrict__ x,
        float* __restrict__ y) {
    int t = threadIdx.x;
    int w = t >> 6;          // wave 0..15
    int wq = w >> 3;         // 0..1: q-pair selector; also K(0)/V(1) stager
    int sp = w & 7;          // key-split 0..7
    int g = (t >> 4) & 3;
    int lr = t & 15;
    int l = t & 63;

    int bid = blockIdx.x;
    int blk = ((bid & 7) << 5) | (bid >> 3);   // XCD swizzle, bijective (256=8*32)
    int b = blk >> 6;                           // 64 blocks per batch
    int q0 = (blk & 63) * 64;                   // 64 tokens per block

    const short* Qb = Qt + (size_t)b * N_TOK * 64;
    const short* Kb = Kt + (size_t)b * N_TOK * 64;
    const short* Vb = Vsw + (size_t)b * 64 * N_TOK;

    __shared__ __align__(16) char LB[8][2][8192];  // [split][buf][K 4KB | V 4KB]
    __shared__ float Ml[32][16];                   // [qt*8+sp][q] l partials
    __shared__ __align__(16) short Olds[64 * 64];  // merged O, swizzled, 8KB

    // Q fragments for this wave's two q-tiles (qt = wq*2 + j)
    bf16x8 qf[2][2];
    #pragma unroll
    for (int j = 0; j < 2; ++j) {
        const short* qp = Qb + (q0 + (wq * 2 + j) * 16 + lr) * 64 + 8 * g;
        qf[j][0] = *(const bf16x8*)qp;
        qf[j][1] = *(const bf16x8*)(qp + 32);
    }

    f32x4 o[2][4];
    #pragma unroll
    for (int j = 0; j < 2; ++j)
        #pragma unroll
        for (int mt = 0; mt < 4; ++mt) o[j][mt] = (f32x4){0.f, 0.f, 0.f, 0.f};
    float la0 = 0.f, la1 = 0.f;

    // staging lane geometry
    int krow = l >> 3;                    // K: row-in-8 per call
    int kchk = ((l & 7) ^ krow) * 8;      // K source chunk (shorts)
    int vrow = l >> 2;                    // V: row-in-16 per call
    int vchk = ((l & 3) ^ (vrow & 3)) * 8;

    auto STAGE = [&](int kt, int buf) {
        int k0s = sp * 512 + kt * 32;
        char* dst0 = &LB[sp][buf][0];
        if (wq == 0) {      // K tile: 32 rows x 128B
            #pragma unroll
            for (int j = 0; j < 4; ++j) {
                const short* src = Kb + (size_t)(k0s + j * 8 + krow) * 64 + kchk;
                __builtin_amdgcn_global_load_lds(
                    (const __attribute__((address_space(1))) void*)src,
                    (__attribute__((address_space(3))) void*)(dst0 + j * 1024),
                    16, 0, 0);
            }
        } else {            // V tile: 64 rows x 64B
            #pragma unroll
            for (int j = 0; j < 4; ++j) {
                const short* src = Vb + (size_t)(j * 16 + vrow) * N_TOK + k0s + vchk;
                __builtin_amdgcn_global_load_lds(
                    (const __attribute__((address_space(1))) void*)src,
                    (__attribute__((address_space(3))) void*)(dst0 + 4096 + j * 1024),
                    16, 0, 0);
            }
        }
    };

    STAGE(0, 0);
    __syncthreads();

    int cK = (g ^ (lr & 7)) << 4;    // K read chunk byte offset (swizzled)
    int cV = (g ^ (lr & 3)) << 4;    // V read chunk byte offset (swizzled)
    int cur = 0;
    for (int kt = 0; kt < 16; ++kt) {
        if (kt < 15) STAGE(kt + 1, cur ^ 1);
        const char* KB_ = &LB[sp][cur][0];
        const char* VB_ = KB_ + 4096;
        // ---- S^T = K·Q^T : row = key (16nt+4g+r), col = query (lr) ----
        f32x4 s[2][2];
        #pragma unroll
        for (int nt = 0; nt < 2; ++nt) {
            const char* rp = KB_ + (nt * 16 + lr) * 128;
            bf16x8 kf0 = *(const bf16x8*)(rp + cK);
            bf16x8 kf1 = *(const bf16x8*)(rp + (cK ^ 64));
            #pragma unroll
            for (int j = 0; j < 2; ++j) {
                f32x4 z = (f32x4){0.f, 0.f, 0.f, 0.f};
                z = __builtin_amdgcn_mfma_f32_16x16x32_bf16(kf0, qf[j][0], z, 0, 0, 0);
                s[j][nt] = __builtin_amdgcn_mfma_f32_16x16x32_bf16(kf1, qf[j][1], z, 0, 0, 0);
            }
        }
        // ---- p = 2^s ; in-lane l accumulation ----
        #pragma unroll
        for (int nt = 0; nt < 2; ++nt)
            #pragma unroll
            for (int r = 0; r < 4; ++r) {
                float p0 = __builtin_amdgcn_exp2f(s[0][nt][r]);
                float p1 = __builtin_amdgcn_exp2f(s[1][nt][r]);
                s[0][nt][r] = p0; la0 += p0;
                s[1][nt][r] = p1; la1 += p1;
            }
        // ---- pack P to bf16 B-fragments via v_cvt_pk_bf16_f32 pairs ----
        union { bf16x8 v; unsigned u[4]; } b0u, b1u;
        b0u.u[0] = pack2(s[0][0][0], s[0][0][1]);
        b0u.u[1] = pack2(s[0][0][2], s[0][0][3]);
        b0u.u[2] = pack2(s[0][1][0], s[0][1][1]);
        b0u.u[3] = pack2(s[0][1][2], s[0][1][3]);
        b1u.u[0] = pack2(s[1][0][0], s[1][0][1]);
        b1u.u[1] = pack2(s[1][0][2], s[1][0][3]);
        b1u.u[2] = pack2(s[1][1][0], s[1][1][1]);
        b1u.u[3] = pack2(s[1][1][2], s[1][1][3]);
        // ---- O^T[d][q] += V·P (V pre-permuted to the same slot order) ----
        #pragma unroll
        for (int mt = 0; mt < 4; ++mt) {
            bf16x8 av = *(const bf16x8*)(VB_ + (mt * 16 + lr) * 64 + cV);
            o[0][mt] = __builtin_amdgcn_mfma_f32_16x16x32_bf16(av, b0u.v, o[0][mt], 0, 0, 0);
            o[1][mt] = __builtin_amdgcn_mfma_f32_16x16x32_bf16(av, b1u.v, o[1][mt], 0, 0, 0);
        }
        __syncthreads();   // staging for kt+1 drained; buf[cur] reads done
        cur ^= 1;
    }
    // ---- l: reduce across the 4 lane-groups ----
    la0 += __shfl_xor(la0, 16); la0 += __shfl_xor(la0, 32);
    la1 += __shfl_xor(la1, 16); la1 += __shfl_xor(la1, 32);
    // ---- partials into (dead) staging LDS, then in-block merge ----
    float* OmL = (float*)&LB[0][0][0];   // [4 qt][8 sp][16 q][64 d] = 128 KB
    #pragma unroll
    for (int j = 0; j < 2; ++j) {
        int qt = wq * 2 + j;
        #pragma unroll
        for (int mt = 0; mt < 4; ++mt)
            *(f32x4*)(OmL + ((qt * 8 + sp) * 16 + lr) * 64 + mt * 16 + 4 * g) = o[j][mt];
        Ml[qt * 8 + sp][lr] = j == 0 ? la0 : la1;
    }
    __syncthreads();
    // ---- merge 8 split-partials, normalize, store O to swizzled LDS ----
    {
        int qt2 = t >> 8, q = (t >> 4) & 15, dq = t & 15;
        float a0 = 0.f, a1 = 0.f, a2 = 0.f, a3 = 0.f, lsum = 0.f;
        #pragma unroll
        for (int s2 = 0; s2 < 8; ++s2) {
            const float* pp = OmL + ((qt2 * 8 + s2) * 16 + q) * 64 + dq * 4;
            float4 v = *(const float4*)pp;
            a0 += v.x; a1 += v.y; a2 += v.z; a3 += v.w;
            lsum += Ml[qt2 * 8 + s2][q];
        }
        float inv = 1.f / lsum;
        int tau = qt2 * 16 + q;           // token index in block (0..63)
        uint2 ow;
        ow.x = pack2(a0 * inv, a1 * inv);
        ow.y = pack2(a2 * inv, a3 * inv);
        // swizzled byte addr: tau*128 + ((chunk ^ (tau&7))<<4) + (dq&1)*8
        char* dst = (char*)Olds + tau * 128 + (((dq >> 1) ^ (tau & 7)) << 4) + (dq & 1) * 8;
        *(uint2*)dst = ow;
    }
    __syncthreads();
    // ---- phase B: y = Wu @ O + bu + x  (verified out_kernel algebra) ----
    {
        int tt = w & 3;            // token sub-tile 0..3
        int cq = w >> 2;           // c quarter 0..3
        int tau = tt * 16 + lr;
        const char* orow = (const char*)Olds + tau * 128;
        bf16x8 a0 = *(const bf16x8*)(orow + ((g ^ (lr & 7)) << 4));
        bf16x8 a1 = *(const bf16x8*)(orow + (((4 + g) ^ (lr & 7)) << 4));
        #pragma unroll
        for (int ct = 0; ct < 4; ++ct) {
            int c = cq * 64 + ct * 16 + lr;
            const short* wp = Wu + (size_t)c * 64 + 8 * g;
            bf16x8 b0 = *(const bf16x8*)wp;
            bf16x8 b1 = *(const bf16x8*)(wp + 32);
            f32x4 acc = (f32x4){0.f, 0.f, 0.f, 0.f};
            acc = __builtin_amdgcn_mfma_f32_16x16x32_bf16(a0, b0, acc, 0, 0, 0);
            acc = __builtin_amdgcn_mfma_f32_16x16x32_bf16(a1, b1, acc, 0, 0, 0);
            float bc = bu[c];
            size_t base = ((size_t)b * CIN + c) * N_TOK + q0 + tt * 16 + 4 * g;
            float4 xr = *(const float4*)(x + base);
            float4 yo;
            yo.x = acc[0] + bc + xr.x;
            yo.y = acc[1] + bc + xr.y;
            yo.z = acc[2] + bc + xr.z;
            yo.w = acc[3] + bc + xr.w;
            *(float4*)(y + base) = yo;
        }
    }
}

extern "C" void kernel_launch(void* const* d_in, const int* in_sizes, int n_in,
                              void* d_out, int out_size, void* d_ws, size_t ws_size,
                              hipStream_t stream) {
    const float* x  = (const float*)d_in[0];
    const float* wk = (const float*)d_in[1];
    const float* bk = (const float*)d_in[2];
    const float* wq = (const float*)d_in[3];
    const float* bq = (const float*)d_in[4];
    const float* wv = (const float*)d_in[5];
    const float* bv = (const float*)d_in[6];
    const float* wu = (const float*)d_in[7];
    const float* bu = (const float*)d_in[8];
    float* out = (float*)d_out;

    char* ws = (char*)d_ws;
    if (ws_size < (size_t)(7u << 20)) return;
    short* Qt  = (short*)(ws);                       // 2 MB  [B][N][64] bf16
    short* Kt  = (short*)(ws + (2u << 20));          // 2 MB
    short* Vd  = (short*)(ws + (4u << 20));          // 2 MB  [B][64][N] bf16 (permuted cols)
    short* Wb  = (short*)(ws + (6u << 20));          // 96 KB [192][256] bf16
    short* Wu  = Wb + 192 * 256;                     // 32 KB [256][64] bf16
    float* bqs = (float*)(Wu + 256 * 64);            // 256 B

    prep_w<<<dim3(64), dim3(256), 0, stream>>>(wq, wk, wv, wu, bq, Wb, Wu, bqs);
    qkv_kernel<<<dim3(512), dim3(256), 0, stream>>>(x, Wb, bqs, bk, bv, Qt, Kt, Vd);
    attn_out_kernel<<<dim3(256), dim3(1024), 0, stream>>>(Qt, Kt, Vd, Wu, bu, x, out);
}

// Round 10
// 56.059 us; speedup vs baseline: 4.8738x; 1.0485x over previous
//
#include <hip/hip_runtime.h>
#include <hip/hip_bf16.h>
#include <math.h>

#define N_TOK 4096
#define CIN 256
#define CBN 64
#define LOG2E 1.44269504f

typedef __attribute__((ext_vector_type(8))) short bf16x8;
typedef __attribute__((ext_vector_type(4))) float f32x4;

static __device__ __forceinline__ unsigned short f2bf(float f) {
    union { float f; unsigned u; } v; v.f = f;
    unsigned r = v.u + 0x7fffu + ((v.u >> 16) & 1u);
    return (unsigned short)(r >> 16);
}
// pair-pack via v_cvt_pk_bf16_f32 (RNE, same as f2bf)
static __device__ __forceinline__ unsigned pack2(float a, float b) {
    float2 t2; t2.x = a; t2.y = b;
    __hip_bfloat162 h = __float22bfloat162_rn(t2);
    union { __hip_bfloat162 h; unsigned u; } cv; cv.h = h;
    return cv.u;
}
static __device__ __forceinline__ float bflo(unsigned u) {
    union { unsigned u; float f; } c; c.u = (u & 0xffffu) << 16; return c.f;
}
static __device__ __forceinline__ float bfhi(unsigned u) {
    union { unsigned u; float f; } c; c.u = u & 0xffff0000u; return c.f;
}

// ---------------- kernel 1: weight prep ----------------
__global__ __launch_bounds__(256) void prep_w(
        const float* __restrict__ wq, const float* __restrict__ wk,
        const float* __restrict__ wv, const float* __restrict__ wu,
        const float* __restrict__ bq,
        short* __restrict__ Wb, short* __restrict__ Wu, float* __restrict__ bqs) {
    int idx = blockIdx.x * 256 + threadIdx.x;   // 0..16383
    int d = idx >> 8, c = idx & 255;            // w*[d][c]
    Wb[d * 256 + c]         = (short)f2bf(wq[idx] * LOG2E);
    Wb[(64 + d) * 256 + c]  = (short)f2bf(wk[idx]);
    Wb[(128 + d) * 256 + c] = (short)f2bf(wv[idx]);
    Wu[idx] = (short)f2bf(wu[idx]);             // wu already [256][64]
    if (idx < 64) bqs[idx] = bq[idx] * LOG2E;
}

// ---------------- kernel 2: QKV projection (MFMA) ----------------
// Q,K token-major [B][N][64]; V d-major [B][64][N] with the verified
// in-32 column permutation col' = 8*((u>>2)&3) + 4*(u>>4) + (u&3).
__global__ __launch_bounds__(256) void qkv_kernel(
        const float* __restrict__ x, const short* __restrict__ Wb,
        const float* __restrict__ bqs, const float* __restrict__ bk, const float* __restrict__ bv,
        short* __restrict__ Qt, short* __restrict__ Kt, short* __restrict__ Vd) {
    int t = threadIdx.x;
    int blk = blockIdx.x;           // 512 = B(4) * 128 token-tiles
    int b = blk >> 7;
    int n0 = (blk & 127) * 32;

    __shared__ short Xs[32][264];   // [tok][c], 528B rows

    {
        int tok4 = t & 7;           // 8 token-quads = 32 tokens
        int cb = t >> 3;            // 32 c per pass
        const float* xb = x + (size_t)b * CIN * N_TOK + n0 + tok4 * 4;
        #pragma unroll
        for (int p = 0; p < 8; ++p) {
            int c = p * 32 + cb;
            float4 xv = *(const float4*)(xb + (size_t)c * N_TOK);
            float xs[4] = {xv.x, xv.y, xv.z, xv.w};
            #pragma unroll
            for (int i = 0; i < 4; ++i)
                Xs[tok4 * 4 + i][c] = (short)f2bf(xs[i]);
        }
    }
    __syncthreads();

    int w = t >> 6;         // wave -> d-tile index (0..3)
    int g = (t >> 4) & 3;
    int lr = t & 15;

    f32x4 acc[3][2];
    #pragma unroll
    for (int m = 0; m < 3; ++m)
        #pragma unroll
        for (int st = 0; st < 2; ++st) acc[m][st] = (f32x4){0.f, 0.f, 0.f, 0.f};
    const short* wbase = Wb + (size_t)(w * 16 + lr) * 256 + 8 * g;
    #pragma unroll
    for (int ks = 0; ks < 8; ++ks) {
        bf16x8 xf0 = *(const bf16x8*)&Xs[lr][ks * 32 + 8 * g];
        bf16x8 xf1 = *(const bf16x8*)&Xs[16 + lr][ks * 32 + 8 * g];
        #pragma unroll
        for (int m = 0; m < 3; ++m) {
            bf16x8 wf = *(const bf16x8*)(wbase + (size_t)m * 64 * 256 + ks * 32);
            acc[m][0] = __builtin_amdgcn_mfma_f32_16x16x32_bf16(wf, xf0, acc[m][0], 0, 0, 0);
            acc[m][1] = __builtin_amdgcn_mfma_f32_16x16x32_bf16(wf, xf1, acc[m][1], 0, 0, 0);
        }
    }
    int d0 = w * 16 + 4 * g;
    float4 bq4 = *(const float4*)(bqs + d0);
    float4 bk4 = *(const float4*)(bk + d0);
    float4 bv4 = *(const float4*)(bv + d0);
    float bvr[4] = {bv4.x, bv4.y, bv4.z, bv4.w};
    #pragma unroll
    for (int st = 0; st < 2; ++st) {
        int tok = n0 + st * 16 + lr;
        size_t qo = ((size_t)b * N_TOK + tok) * 64 + d0;
        uint2 qp, kp;
        qp.x = pack2(acc[0][st][0] + bq4.x, acc[0][st][1] + bq4.y);
        qp.y = pack2(acc[0][st][2] + bq4.z, acc[0][st][3] + bq4.w);
        kp.x = pack2(acc[1][st][0] + bk4.x, acc[1][st][1] + bk4.y);
        kp.y = pack2(acc[1][st][2] + bk4.z, acc[1][st][3] + bk4.w);
        *(uint2*)(Qt + qo) = qp;
        *(uint2*)(Kt + qo) = kp;
        int u = tok & 31;
        int vcol = (tok & ~31) + 8 * ((u >> 2) & 3) + 4 * (u >> 4) + (u & 3);
        #pragma unroll
        for (int r = 0; r < 4; ++r)
            Vd[((size_t)b * 64 + d0 + r) * N_TOK + vcol] = (short)f2bf(acc[2][st][r] + bvr[r]);
    }
}

// ---------------- kernel 3: attention over a key-half ----------
// 512 blocks x 512 thr (2 blocks/CU co-resident): block = 64 queries x
// 2048 keys (half). 8 waves = 2 wq x 4 sp; per-wave loop identical to R9
// (proven): 32-key double-buffered LDS tiles via global_load_lds with XOR
// chunk-swizzle (global source + ds_read side). In-block 4-way split merge
// (XOR-swizzled Om chunks -> no bank conflicts), then UNNORMALIZED bf16
// partial O + l written to global scratch.
__global__ __launch_bounds__(512, 4) void attn_half_kernel(
        const short* __restrict__ Qt, const short* __restrict__ Kt,
        const short* __restrict__ Vsw, short* __restrict__ Oh,
        float* __restrict__ lh) {
    int t = threadIdx.x;
    int w = t >> 6;          // wave 0..7
    int wq = w >> 2;         // 0..1: q-pair selector; also K(0)/V(1) stager
    int sp = w & 3;          // key-split 0..3 (512 keys each)
    int g = (t >> 4) & 3;
    int lr = t & 15;
    int l = t & 63;

    int bid = blockIdx.x;
    int swz = ((bid & 7) << 6) | (bid >> 3);   // XCD swizzle, bijective (512=8*64)
    int b = swz >> 7;                           // 128 blocks per batch
    int rem = swz & 127;
    int q0 = (rem >> 1) * 64;                   // 64 tokens per block
    int half = rem & 1;
    int kbase = half * 2048;

    const short* Qb = Qt + (size_t)b * N_TOK * 64;
    const short* Kb = Kt + (size_t)b * N_TOK * 64;
    const short* Vb = Vsw + (size_t)b * 64 * N_TOK;

    __shared__ __align__(16) char LB[4][2][8192];  // [split][buf][K 4KB | V 4KB]
    __shared__ float Ml[16][16];                   // [qt*4+sp][q] l partials

    // Q fragments for this wave's two q-tiles (qt = wq*2 + j)
    bf16x8 qf[2][2];
    #pragma unroll
    for (int j = 0; j < 2; ++j) {
        const short* qp = Qb + (q0 + (wq * 2 + j) * 16 + lr) * 64 + 8 * g;
        qf[j][0] = *(const bf16x8*)qp;
        qf[j][1] = *(const bf16x8*)(qp + 32);
    }

    f32x4 o[2][4];
    #pragma unroll
    for (int j = 0; j < 2; ++j)
        #pragma unroll
        for (int mt = 0; mt < 4; ++mt) o[j][mt] = (f32x4){0.f, 0.f, 0.f, 0.f};
    float la0 = 0.f, la1 = 0.f;

    // staging lane geometry
    int krow = l >> 3;                    // K: row-in-8 per call
    int kchk = ((l & 7) ^ krow) * 8;      // K source chunk (shorts)
    int vrow = l >> 2;                    // V: row-in-16 per call
    int vchk = ((l & 3) ^ (vrow & 3)) * 8;

    auto STAGE = [&](int kt, int buf) {
        int k0s = kbase + sp * 512 + kt * 32;
        char* dst0 = &LB[sp][buf][0];
        if (wq == 0) {      // K tile: 32 rows x 128B
            #pragma unroll
            for (int j = 0; j < 4; ++j) {
                const short* src = Kb + (size_t)(k0s + j * 8 + krow) * 64 + kchk;
                __builtin_amdgcn_global_load_lds(
                    (const __attribute__((address_space(1))) void*)src,
                    (__attribute__((address_space(3))) void*)(dst0 + j * 1024),
                    16, 0, 0);
            }
        } else {            // V tile: 64 rows x 64B
            #pragma unroll
            for (int j = 0; j < 4; ++j) {
                const short* src = Vb + (size_t)(j * 16 + vrow) * N_TOK + k0s + vchk;
                __builtin_amdgcn_global_load_lds(
                    (const __attribute__((address_space(1))) void*)src,
                    (__attribute__((address_space(3))) void*)(dst0 + 4096 + j * 1024),
                    16, 0, 0);
            }
        }
    };

    STAGE(0, 0);
    __syncthreads();

    int cK = (g ^ (lr & 7)) << 4;    // K read chunk byte offset (swizzled)
    int cV = (g ^ (lr & 3)) << 4;    // V read chunk byte offset (swizzled)
    int cur = 0;
    for (int kt = 0; kt < 16; ++kt) {
        if (kt < 15) STAGE(kt + 1, cur ^ 1);
        const char* KB_ = &LB[sp][cur][0];
        const char* VB_ = KB_ + 4096;
        // ---- S^T = K·Q^T : row = key (16nt+4g+r), col = query (lr) ----
        f32x4 s[2][2];
        #pragma unroll
        for (int nt = 0; nt < 2; ++nt) {
            const char* rp = KB_ + (nt * 16 + lr) * 128;
            bf16x8 kf0 = *(const bf16x8*)(rp + cK);
            bf16x8 kf1 = *(const bf16x8*)(rp + (cK ^ 64));
            #pragma unroll
            for (int j = 0; j < 2; ++j) {
                f32x4 z = (f32x4){0.f, 0.f, 0.f, 0.f};
                z = __builtin_amdgcn_mfma_f32_16x16x32_bf16(kf0, qf[j][0], z, 0, 0, 0);
                s[j][nt] = __builtin_amdgcn_mfma_f32_16x16x32_bf16(kf1, qf[j][1], z, 0, 0, 0);
            }
        }
        // ---- p = 2^s ; in-lane l accumulation ----
        #pragma unroll
        for (int nt = 0; nt < 2; ++nt)
            #pragma unroll
            for (int r = 0; r < 4; ++r) {
                float p0 = __builtin_amdgcn_exp2f(s[0][nt][r]);
                float p1 = __builtin_amdgcn_exp2f(s[1][nt][r]);
                s[0][nt][r] = p0; la0 += p0;
                s[1][nt][r] = p1; la1 += p1;
            }
        // ---- pack P to bf16 B-fragments via v_cvt_pk_bf16_f32 ----
        union { bf16x8 v; unsigned u[4]; } b0u, b1u;
        b0u.u[0] = pack2(s[0][0][0], s[0][0][1]);
        b0u.u[1] = pack2(s[0][0][2], s[0][0][3]);
        b0u.u[2] = pack2(s[0][1][0], s[0][1][1]);
        b0u.u[3] = pack2(s[0][1][2], s[0][1][3]);
        b1u.u[0] = pack2(s[1][0][0], s[1][0][1]);
        b1u.u[1] = pack2(s[1][0][2], s[1][0][3]);
        b1u.u[2] = pack2(s[1][1][0], s[1][1][1]);
        b1u.u[3] = pack2(s[1][1][2], s[1][1][3]);
        // ---- O^T[d][q] += V·P (V pre-permuted to the same slot order) ----
        #pragma unroll
        for (int mt = 0; mt < 4; ++mt) {
            bf16x8 av = *(const bf16x8*)(VB_ + (mt * 16 + lr) * 64 + cV);
            o[0][mt] = __builtin_amdgcn_mfma_f32_16x16x32_bf16(av, b0u.v, o[0][mt], 0, 0, 0);
            o[1][mt] = __builtin_amdgcn_mfma_f32_16x16x32_bf16(av, b1u.v, o[1][mt], 0, 0, 0);
        }
        __syncthreads();   // staging for kt+1 drained; buf[cur] reads done
        cur ^= 1;
    }
    // ---- l: reduce across the 4 lane-groups ----
    la0 += __shfl_xor(la0, 16); la0 += __shfl_xor(la0, 32);
    la1 += __shfl_xor(la1, 16); la1 += __shfl_xor(la1, 32);
    // ---- partials into (dead) staging LDS, XOR-swizzled chunks ----
    float* OmL = (float*)&LB[0][0][0];   // [4 qt][4 sp][16 q][64 d] = 64 KB
    #pragma unroll
    for (int j = 0; j < 2; ++j) {
        int qt = wq * 2 + j;
        int row = (qt * 4 + sp) * 16 + lr;
        #pragma unroll
        for (int mt = 0; mt < 4; ++mt) {
            int c = mt * 4 + g;
            int cs = (c & 8) | ((c & 7) ^ (lr & 7));
            *(f32x4*)(OmL + (size_t)row * 64 + cs * 4) = o[j][mt];
        }
        Ml[qt * 4 + sp][lr] = j == 0 ? la0 : la1;
    }
    __syncthreads();
    // ---- merge 4 split-partials; write UNNORMALIZED bf16 O + l ----
    {
        int qt2 = t >> 7;          // 0..3
        int q = (t >> 3) & 15;     // 0..15
        int dh = t & 7;            // d-octet 0..7
        int dq0 = dh * 2, dq1 = dq0 + 1;
        int cs0 = (dq0 & 8) | ((dq0 & 7) ^ (q & 7));
        int cs1 = (dq1 & 8) | ((dq1 & 7) ^ (q & 7));
        f32x4 a0 = (f32x4){0.f,0.f,0.f,0.f}, a1 = (f32x4){0.f,0.f,0.f,0.f};
        float lsum = 0.f;
        #pragma unroll
        for (int s2 = 0; s2 < 4; ++s2) {
            int row = (qt2 * 4 + s2) * 16 + q;
            f32x4 v0 = *(const f32x4*)(OmL + (size_t)row * 64 + cs0 * 4);
            f32x4 v1 = *(const f32x4*)(OmL + (size_t)row * 64 + cs1 * 4);
            a0 += v0; a1 += v1;
            lsum += Ml[qt2 * 4 + s2][q];
        }
        int tok = q0 + qt2 * 16 + q;
        uint4 ow;
        ow.x = pack2(a0[0], a0[1]);
        ow.y = pack2(a0[2], a0[3]);
        ow.z = pack2(a1[0], a1[1]);
        ow.w = pack2(a1[2], a1[3]);
        *(uint4*)(Oh + ((size_t)(half * 4 + b) * N_TOK + tok) * 64 + dh * 8) = ow;
        if (dh == 0) lh[(size_t)(half * 4 + b) * N_TOK + tok] = lsum;
    }
}

// ---------------- kernel 4: half-merge + up-projection + residual --------
// 256 blocks x 512 thr. Sum the two key-half partials, normalize, store
// O to XOR-swizzled LDS, then y = Wu @ O + bu + x (verified phase-B algebra).
__global__ __launch_bounds__(512, 4) void mergeup_kernel(
        const short* __restrict__ Oh, const float* __restrict__ lh,
        const short* __restrict__ Wu, const float* __restrict__ bu,
        const float* __restrict__ x, float* __restrict__ y) {
    int t = threadIdx.x;
    int blk = blockIdx.x;      // 256 = B(4) * 64 tok-tiles
    int b = blk >> 6;
    int q0 = (blk & 63) * 64;

    __shared__ __align__(16) short Olds[64 * 64];   // swizzled, 8KB

    {
        int qt2 = t >> 7, q = (t >> 3) & 15, dh = t & 7;
        int tok = q0 + qt2 * 16 + q;
        size_t o0 = ((size_t)b * N_TOK + tok) * 64 + dh * 8;
        size_t o1 = ((size_t)(4 + b) * N_TOK + tok) * 64 + dh * 8;
        uint4 u0 = *(const uint4*)(Oh + o0);
        uint4 u1 = *(const uint4*)(Oh + o1);
        float inv = 1.f / (lh[(size_t)b * N_TOK + tok] + lh[(size_t)(4 + b) * N_TOK + tok]);
        unsigned uu0[4] = {u0.x, u0.y, u0.z, u0.w};
        unsigned uu1[4] = {u1.x, u1.y, u1.z, u1.w};
        unsigned outw[4];
        #pragma unroll
        for (int i = 0; i < 4; ++i)
            outw[i] = pack2((bflo(uu0[i]) + bflo(uu1[i])) * inv,
                            (bfhi(uu0[i]) + bfhi(uu1[i])) * inv);
        int tau = qt2 * 16 + q;
        uint4 ow; ow.x = outw[0]; ow.y = outw[1]; ow.z = outw[2]; ow.w = outw[3];
        *(uint4*)((char*)Olds + tau * 128 + ((dh ^ (tau & 7)) << 4)) = ow;
    }
    __syncthreads();
    // ---- phase B: y = Wu @ O + bu + x ----
    {
        int w = t >> 6, g = (t >> 4) & 3, lr = t & 15;
        int tt = w & 3;            // token sub-tile 0..3
        int ch = w >> 2;           // c half 0..1 (128 c each)
        int tau = tt * 16 + lr;
        const char* orow = (const char*)Olds + tau * 128;
        bf16x8 a0 = *(const bf16x8*)(orow + ((g ^ (tau & 7)) << 4));
        bf16x8 a1 = *(const bf16x8*)(orow + (((4 + g) ^ (tau & 7)) << 4));
        #pragma unroll
        for (int ct = 0; ct < 8; ++ct) {
            int c = ch * 128 + ct * 16 + lr;
            const short* wp = Wu + (size_t)c * 64 + 8 * g;
            bf16x8 b0 = *(const bf16x8*)wp;
            bf16x8 b1 = *(const bf16x8*)(wp + 32);
            f32x4 acc = (f32x4){0.f, 0.f, 0.f, 0.f};
            acc = __builtin_amdgcn_mfma_f32_16x16x32_bf16(a0, b0, acc, 0, 0, 0);
            acc = __builtin_amdgcn_mfma_f32_16x16x32_bf16(a1, b1, acc, 0, 0, 0);
            float bc = bu[c];
            size_t base = ((size_t)b * CIN + c) * N_TOK + q0 + tt * 16 + 4 * g;
            float4 xr = *(const float4*)(x + base);
            float4 yo;
            yo.x = acc[0] + bc + xr.x;
            yo.y = acc[1] + bc + xr.y;
            yo.z = acc[2] + bc + xr.z;
            yo.w = acc[3] + bc + xr.w;
            *(float4*)(y + base) = yo;
        }
    }
}

extern "C" void kernel_launch(void* const* d_in, const int* in_sizes, int n_in,
                              void* d_out, int out_size, void* d_ws, size_t ws_size,
                              hipStream_t stream) {
    const float* x  = (const float*)d_in[0];
    const float* wk = (const float*)d_in[1];
    const float* bk = (const float*)d_in[2];
    const float* wq = (const float*)d_in[3];
    const float* bq = (const float*)d_in[4];
    const float* wv = (const float*)d_in[5];
    const float* bv = (const float*)d_in[6];
    const float* wu = (const float*)d_in[7];
    const float* bu = (const float*)d_in[8];
    float* out = (float*)d_out;

    char* ws = (char*)d_ws;
    if (ws_size < (size_t)10748160u) return;   // proven available (R4 ran with 10.75MB req)
    short* Qt  = (short*)(ws);                        // 2 MB  [B][N][64] bf16
    short* Kt  = (short*)(ws + 2097152u);             // 2 MB
    short* Vd  = (short*)(ws + 4194304u);             // 2 MB  [B][64][N] bf16 (permuted cols)
    short* Oh  = (short*)(ws + 6291456u);             // 4 MB  [2 half][B][N][64] bf16 partials
    float* lh  = (float*)(ws + 10485760u);            // 128 KB [2][B][N] f32
    short* Wb  = (short*)(ws + 10616832u);            // 96 KB [192][256] bf16
    short* Wu  = (short*)(ws + 10715136u);            // 32 KB [256][64] bf16
    float* bqs = (float*)(ws + 10747904u);            // 256 B

    prep_w<<<dim3(64), dim3(256), 0, stream>>>(wq, wk, wv, wu, bq, Wb, Wu, bqs);
    qkv_kernel<<<dim3(512), dim3(256), 0, stream>>>(x, Wb, bqs, bk, bv, Qt, Kt, Vd);
    attn_half_kernel<<<dim3(512), dim3(512), 0, stream>>>(Qt, Kt, Vd, Oh, lh);
    mergeup_kernel<<<dim3(256), dim3(512), 0, stream>>>(Oh, lh, Wu, bu, x, out);
}